// Round 5
// baseline (642.341 us; speedup 1.0000x reference)
//
#include <hip/hip_runtime.h>
#include <hip/hip_bf16.h>

typedef unsigned short u16;
typedef unsigned int u32;
typedef __attribute__((ext_vector_type(8))) short bf16x8;
typedef __attribute__((ext_vector_type(4))) float f32x4;
typedef __attribute__((ext_vector_type(4))) u16 u16x4;

#define DEV static __device__ __forceinline__

DEV u16 f2bf(float x) {
  unsigned u = __builtin_bit_cast(unsigned, x);
  u += 0x7fffu + ((u >> 16) & 1u);   // RNE (finite values)
  return (u16)(u >> 16);
}
DEV float bf2f(u16 u) { return __builtin_bit_cast(float, ((unsigned)u) << 16); }

DEV void glds16(const u16* g, u16* l) {
  __builtin_amdgcn_global_load_lds(
      (const __attribute__((address_space(1))) void*)g,
      (__attribute__((address_space(3))) void*)l, 16, 0, 0);
}

// ---- X convert: k,v,q fp32 -> Xb bf16 [3][8388608] (order: k, v, q) ----
__global__ __launch_bounds__(256) void xcvt(
    const float* __restrict__ k, const float* __restrict__ v,
    const float* __restrict__ q, u16* __restrict__ Xb) {
  const size_t i0 = (size_t)blockIdx.x * 256 + threadIdx.x;
  for (size_t t = i0; t < 6291456; t += 524288) {
    const size_t e = t * 4;
    const float* src = (e < 8388608) ? k + e
                     : (e < 16777216) ? v + (e - 8388608)
                     : q + (e - 16777216);
    const f32x4 x = *(const f32x4*)src;
    u16x4 o;
#pragma unroll
    for (int r = 0; r < 4; ++r) o[r] = f2bf(x[r]);
    *(u16x4*)&Xb[e] = o;
  }
}

// ---- transpose+convert weights: out_bf16[n*1024+k] = in_f32[k*1024+n] ----
__global__ __launch_bounds__(256) void transpose_w(
    const float* __restrict__ w0, const float* __restrict__ w1,
    const float* __restrict__ w2, const float* __restrict__ w3,
    u16* __restrict__ out) {
  __shared__ u16 tile[32][33];
  const int mat = blockIdx.y;
  const float* in = (mat == 0) ? w0 : (mat == 1) ? w1 : (mat == 2) ? w2 : w3;
  u16* o = out + (size_t)mat * 1048576;
  const int bk = ((int)blockIdx.x & 31) << 5;
  const int bn = ((int)blockIdx.x >> 5) << 5;
  const int tx = threadIdx.x & 31, ty = threadIdx.x >> 5;
#pragma unroll
  for (int i = 0; i < 32; i += 8)
    tile[ty + i][tx] = f2bf(in[(size_t)(bk + ty + i) * 1024 + bn + tx]);
  __syncthreads();
#pragma unroll
  for (int i = 0; i < 32; i += 8)
    o[(size_t)(bn + ty + i) * 1024 + bk + tx] = tile[tx][ty + i];
}

// ---- m97-style GEMM: 128x128 tile, BK=32, global_load_lds staging ----
__global__ __launch_bounds__(256) void gemm_qkv(
    const u16* __restrict__ Xb, const u16* __restrict__ WTall,
    const float* __restrict__ bK, const float* __restrict__ bV,
    const float* __restrict__ bQ,
    u16* __restrict__ Kup, u16* __restrict__ VupT, u16* __restrict__ Qup) {
  __shared__ u16 As[4096];   // [128][32] linear
  __shared__ u16 Bs[4096];
  const int mode = blockIdx.y;
  const u16* A = Xb + (size_t)mode * 8388608;
  const u16* Bw = WTall + (size_t)mode * 1048576;
  const float* bias = (mode == 0) ? bK : (mode == 1) ? bV : bQ;

  const int tid = threadIdx.x;
  const int w = tid >> 6, l = tid & 63;
  const int ln = l & 15, lg = l >> 4, kg8 = lg << 3;
  const int wr = w >> 1, wc = w & 1;
  const int mb = ((int)blockIdx.x >> 3) << 7;
  const int nb = ((int)blockIdx.x & 7) << 7;

  const int srow = (w << 5) + (l >> 2);
  const int sseg = (l & 3) << 3;
  const u16* Ag0 = A + (size_t)(mb + srow) * 1024 + sseg;
  const u16* Bg0 = Bw + (size_t)(nb + srow) * 1024 + sseg;
  u16* Al0 = As + srow * 32 + sseg;
  u16* Bl0 = Bs + srow * 32 + sseg;

  f32x4 acc[4][4] = {};
  const int ar = (wr << 6) + ln;
  const int br = (wc << 6) + ln;

  for (int k0 = 0; k0 < 1024; k0 += 32) {
    glds16(Ag0 + k0, Al0);
    glds16(Ag0 + 16384 + k0, Al0 + 512);
    glds16(Bg0 + k0, Bl0);
    glds16(Bg0 + 16384 + k0, Bl0 + 512);
    __syncthreads();
    bf16x8 aa[4], bb[4];
#pragma unroll
    for (int mt = 0; mt < 4; ++mt) aa[mt] = *(const bf16x8*)&As[(ar + (mt << 4)) * 32 + kg8];
#pragma unroll
    for (int nt = 0; nt < 4; ++nt) bb[nt] = *(const bf16x8*)&Bs[(br + (nt << 4)) * 32 + kg8];
#pragma unroll
    for (int mt = 0; mt < 4; ++mt)
#pragma unroll
      for (int nt = 0; nt < 4; ++nt)
        acc[mt][nt] = __builtin_amdgcn_mfma_f32_16x16x32_bf16(aa[mt], bb[nt], acc[mt][nt], 0, 0, 0);
    __syncthreads();
  }

  const float scale = (mode == 2) ? 0.125f : 1.0f;
#pragma unroll
  for (int mt = 0; mt < 4; ++mt) {
    const int m0 = mb + (wr << 6) + (mt << 4) + (lg << 2);
    const int bb_ = m0 >> 10, s0 = m0 & 1023;
#pragma unroll
    for (int nt = 0; nt < 4; ++nt) {
      const int n = nb + (wc << 6) + (nt << 4) + ln;
      const float bval = bias[n];
      const int h = n >> 6, dh = n & 63;
      if (mode == 1) {
        u16x4 pk;
#pragma unroll
        for (int r = 0; r < 4; ++r) pk[r] = f2bf(acc[mt][nt][r] + bval);
        *(u16x4*)&VupT[(((size_t)(bb_ * 16 + h) << 6) + dh) * 1024 + s0] = pk;
      } else {
        u16* Y = (mode == 0) ? Kup : Qup;
#pragma unroll
        for (int r = 0; r < 4; ++r)
          Y[(((size_t)(bb_ * 16 + h) << 10) + s0 + r) * 64 + dh] =
              f2bf((acc[mt][nt][r] + bval) * scale);
      }
    }
  }
}

// ---- out-proj: Out_f32 = Ctx_bf16 @ WoT + bo ----
__global__ __launch_bounds__(256) void gemm_out(
    const u16* __restrict__ Ctx, const u16* __restrict__ WTall,
    const float* __restrict__ bO, float* __restrict__ Out) {
  __shared__ u16 As[4096];
  __shared__ u16 Bs[4096];
  const u16* Bw = WTall + 3145728;

  const int tid = threadIdx.x;
  const int w = tid >> 6, l = tid & 63;
  const int ln = l & 15, lg = l >> 4, kg8 = lg << 3;
  const int wr = w >> 1, wc = w & 1;
  const int mb = ((int)blockIdx.x >> 3) << 7;
  const int nb = ((int)blockIdx.x & 7) << 7;

  const int srow = (w << 5) + (l >> 2);
  const int sseg = (l & 3) << 3;
  const u16* Ag0 = Ctx + (size_t)(mb + srow) * 1024 + sseg;
  const u16* Bg0 = Bw + (size_t)(nb + srow) * 1024 + sseg;
  u16* Al0 = As + srow * 32 + sseg;
  u16* Bl0 = Bs + srow * 32 + sseg;

  f32x4 acc[4][4] = {};
  const int ar = (wr << 6) + ln;
  const int br = (wc << 6) + ln;

  for (int k0 = 0; k0 < 1024; k0 += 32) {
    glds16(Ag0 + k0, Al0);
    glds16(Ag0 + 16384 + k0, Al0 + 512);
    glds16(Bg0 + k0, Bl0);
    glds16(Bg0 + 16384 + k0, Bl0 + 512);
    __syncthreads();
    bf16x8 aa[4], bb[4];
#pragma unroll
    for (int mt = 0; mt < 4; ++mt) aa[mt] = *(const bf16x8*)&As[(ar + (mt << 4)) * 32 + kg8];
#pragma unroll
    for (int nt = 0; nt < 4; ++nt) bb[nt] = *(const bf16x8*)&Bs[(br + (nt << 4)) * 32 + kg8];
#pragma unroll
    for (int mt = 0; mt < 4; ++mt)
#pragma unroll
      for (int nt = 0; nt < 4; ++nt)
        acc[mt][nt] = __builtin_amdgcn_mfma_f32_16x16x32_bf16(aa[mt], bb[nt], acc[mt][nt], 0, 0, 0);
    __syncthreads();
  }
#pragma unroll
  for (int mt = 0; mt < 4; ++mt) {
    const int m0 = mb + (wr << 6) + (mt << 4) + (lg << 2);
#pragma unroll
    for (int nt = 0; nt < 4; ++nt) {
      const int n = nb + (wc << 6) + (nt << 4) + ln;
      const float bval = bO[n];
#pragma unroll
      for (int r = 0; r < 4; ++r)
        Out[(size_t)(m0 + r) * 1024 + n] = acc[mt][nt][r] + bval;
    }
  }
}

// ---- attention, register-lean: unnormalized exp in LDS, inv deferred ----
// HPB=1: one head/block, grid 8192, plane per head (16 planes).
// HPB=2: head pair/block, grid 4096, bf16-packed pair accumulator (8 planes).
template <int HPB>
__global__ __launch_bounds__(256) void attn_kernel(
    const u16* __restrict__ Qup, const u16* __restrict__ Kup,
    const u16* __restrict__ VupT, const int* __restrict__ mask,
    u16* __restrict__ Ctx, u16* __restrict__ Pp) {
  __shared__ u16 P_lds[16 * 1024];   // unnormalized probs, XOR-swizzled rows
  __shared__ float red[4][16];
  __shared__ float invs[16];

  const int tid = threadIdx.x;
  const int w = tid >> 6, l = tid & 63;
  const int ln = l & 15, lg = l >> 4, kg8 = lg << 3;

  // XCD-bijective swizzle: each XCD owns 2 heads for all (b, qtile)
  // -> its K+V working set = 4 MB = one XCD L2.
  const int bid = (int)blockIdx.x;
  int qb, b, hbase;
  if (HPB == 1) {
    const int swz = ((bid & 7) << 10) | (bid >> 3);
    qb = (swz & 63) << 4; b = (swz >> 6) & 7; hbase = swz >> 9;
  } else {
    const int swz = ((bid & 7) << 9) | (bid >> 3);
    qb = (swz & 63) << 4; b = (swz >> 6) & 7; hbase = (swz >> 9) << 1;
  }
  const int pi = (HPB == 1) ? hbase : (hbase >> 1);   // plane index

  // mask bits: bit (t*4+r) for (row = 4*lg+r, key = w*256 + t*16 + ln)
  const int* Mp = mask + ((size_t)b << 20) + ((size_t)qb << 10);
  unsigned long long mbits = 0ull;
#pragma unroll
  for (int t = 0; t < 16; ++t) {
    const int key = (w << 8) + (t << 4) + ln;
#pragma unroll
    for (int r = 0; r < 4; ++r) {
      const int row = (lg << 2) + r;
      if (Mp[((size_t)row << 10) + key] != 0) mbits |= 1ull << ((t << 2) + r);
    }
  }

  bf16x8 accv[8];   // HPB==2 only: bf16 partial plane, row = tid>>4 layout

  for (int hh = 0; hh < HPB; ++hh) {
    const int h = hbase + hh;
    const size_t bh = (size_t)(b * 16 + h);
    const u16* Qp = Qup + ((bh << 10) + qb) * 64;
    const u16* Kp = Kup + (bh << 10) * 64;

    const bf16x8 qa0 = *(const bf16x8*)&Qp[ln * 64 + kg8];
    const bf16x8 qa1 = *(const bf16x8*)&Qp[ln * 64 + 32 + kg8];

    // QK^T: wave w owns keys [w*256, w*256+256)
    f32x4 sc[16];
#pragma unroll
    for (int t = 0; t < 16; ++t) {
      const int key = (w << 8) + (t << 4) + ln;
      const bf16x8 kb0 = *(const bf16x8*)&Kp[(size_t)key * 64 + kg8];
      const bf16x8 kb1 = *(const bf16x8*)&Kp[(size_t)key * 64 + 32 + kg8];
      f32x4 c = {0, 0, 0, 0};
      c = __builtin_amdgcn_mfma_f32_16x16x32_bf16(qa0, kb0, c, 0, 0, 0);
      c = __builtin_amdgcn_mfma_f32_16x16x32_bf16(qa1, kb1, c, 0, 0, 0);
      sc[t] = c;
    }

    // mask + row max
    float rmax[4] = {-3.0e38f, -3.0e38f, -3.0e38f, -3.0e38f};
#pragma unroll
    for (int t = 0; t < 16; ++t)
#pragma unroll
      for (int r = 0; r < 4; ++r) {
        const float s = ((mbits >> ((t << 2) + r)) & 1ull) ? -3.0e38f : sc[t][r];
        sc[t][r] = s;
        rmax[r] = fmaxf(rmax[r], s);
      }
#pragma unroll
    for (int off = 1; off < 16; off <<= 1) {
#pragma unroll
      for (int r = 0; r < 4; ++r) rmax[r] = fmaxf(rmax[r], __shfl_xor(rmax[r], off));
    }
    if (ln == 0) {
#pragma unroll
      for (int r = 0; r < 4; ++r) red[w][(lg << 2) + r] = rmax[r];
    }
    __syncthreads();                                   // A
    float mrow[4];
#pragma unroll
    for (int r = 0; r < 4; ++r) {
      const int row = (lg << 2) + r;
      mrow[r] = fmaxf(fmaxf(red[0][row], red[1][row]), fmaxf(red[2][row], red[3][row]));
    }
    // exp (UNNORMALIZED, kept in sc) + row sum
    float rsum[4] = {0, 0, 0, 0};
#pragma unroll
    for (int t = 0; t < 16; ++t)
#pragma unroll
      for (int r = 0; r < 4; ++r) {
        const float p = __expf(sc[t][r] - mrow[r]);
        sc[t][r] = p;
        rsum[r] += p;
      }
#pragma unroll
    for (int off = 1; off < 16; off <<= 1) {
#pragma unroll
      for (int r = 0; r < 4; ++r) rsum[r] += __shfl_xor(rsum[r], off);
    }
    __syncthreads();                                   // B (mrow reads done)
    if (ln == 0) {
#pragma unroll
      for (int r = 0; r < 4; ++r) red[w][(lg << 2) + r] = rsum[r];
    }
    __syncthreads();                                   // C
    float inv[4];
#pragma unroll
    for (int r = 0; r < 4; ++r) {
      const int row = (lg << 2) + r;
      inv[r] = 1.0f / (red[0][row] + red[1][row] + red[2][row] + red[3][row]);
    }
    if (w == 0 && ln == 0) {
#pragma unroll
      for (int r = 0; r < 4; ++r) invs[(lg << 2) + r] = inv[r];
    }

    // write unnormalized exp to LDS (bf16, swizzled)
#pragma unroll
    for (int t = 0; t < 16; ++t) {
      const int key = (w << 8) + (t << 4) + ln;
#pragma unroll
      for (int r = 0; r < 4; ++r) {
        const int row = (lg << 2) + r;
        const int bo_ = ((row << 11) + (key << 1)) ^ ((row & 7) << 4);
        *(u16*)((char*)P_lds + bo_) = f2bf(sc[t][r]);
      }
    }
    __syncthreads();                                   // D

    // PV on unnormalized P; normalize by inv at the epilogue.
    f32x4 c0 = {0, 0, 0, 0}, c1 = {0, 0, 0, 0};
    const u16* vrow = VupT + ((bh << 6) + (w << 4) + ln) * 1024;
#pragma unroll
    for (int kk = 0; kk < 32; kk += 2) {
      const int a0 = ((ln << 11) + (((kk << 5) + kg8) << 1)) ^ ((ln & 7) << 4);
      const int a1 = ((ln << 11) + ((((kk + 1) << 5) + kg8) << 1)) ^ ((ln & 7) << 4);
      const bf16x8 pa0 = *(const bf16x8*)((const char*)P_lds + a0);
      const bf16x8 pa1 = *(const bf16x8*)((const char*)P_lds + a1);
      const bf16x8 vb0 = *(const bf16x8*)&vrow[(kk << 5) + kg8];
      const bf16x8 vb1 = *(const bf16x8*)&vrow[((kk + 1) << 5) + kg8];
      c0 = __builtin_amdgcn_mfma_f32_16x16x32_bf16(pa0, vb0, c0, 0, 0, 0);
      c1 = __builtin_amdgcn_mfma_f32_16x16x32_bf16(pa1, vb1, c1, 0, 0, 0);
    }
#pragma unroll
    for (int r = 0; r < 4; ++r) {
      const int row = (lg << 2) + r;
      Ctx[(((size_t)b << 10) + qb + row) * 1024 + (h << 6) + (w << 4) + ln] =
          f2bf((c0[r] + c1[r]) * inv[r]);
    }

    // attn_mean plane: readback P_lds * invs[row], coalesced
    {
      const int row = tid >> 4;
      const float iv = invs[row];
      u16* Pg = Pp + ((size_t)pi << 23) + (((size_t)b << 10) + qb + row) * 1024;
#pragma unroll
      for (int i = 0; i < 8; ++i) {
        const int chunk = (tid & 15) + (i << 4);
        const int bo_ = ((row << 11) + (chunk << 4)) ^ ((row & 7) << 4);
        const bf16x8 pv = *(const bf16x8*)((const char*)P_lds + bo_);
        if constexpr (HPB == 1) {
          bf16x8 o;
#pragma unroll
          for (int e = 0; e < 8; ++e) o[e] = (short)f2bf(bf2f((u16)pv[e]) * iv);
          *(bf16x8*)&Pg[chunk << 3] = o;
        } else {
          if (hh == 0) {
            bf16x8 o;
#pragma unroll
            for (int e = 0; e < 8; ++e) o[e] = (short)f2bf(bf2f((u16)pv[e]) * iv);
            accv[i] = o;
          } else {
            bf16x8 o;
#pragma unroll
            for (int e = 0; e < 8; ++e)
              o[e] = (short)f2bf(bf2f((u16)accv[i][e]) + bf2f((u16)pv[e]) * iv);
            *(bf16x8*)&Pg[chunk << 3] = o;
          }
        }
      }
    }
    __syncthreads();                                   // E (P_lds/red/invs reuse)
  }
}

// ---- combine: amean = sum of np planes / 16, fp32 out ----
__global__ __launch_bounds__(256) void combine(
    const u16* __restrict__ Pp, int np, float* __restrict__ Am) {
  const size_t i = ((size_t)blockIdx.x * 256 + threadIdx.x) * 8;
  float s[8] = {0, 0, 0, 0, 0, 0, 0, 0};
  for (int p = 0; p < np; ++p) {
    const u16x4* q = (const u16x4*)&Pp[(size_t)p * 8388608 + i];
    const u16x4 a = q[0], c = q[1];
#pragma unroll
    for (int r = 0; r < 4; ++r) { s[r] += bf2f(a[r]); s[r + 4] += bf2f(c[r]); }
  }
  f32x4 lo, hi;
#pragma unroll
  for (int r = 0; r < 4; ++r) { lo[r] = s[r] * 0.0625f; hi[r] = s[r + 4] * 0.0625f; }
  *(f32x4*)&Am[i] = lo;
  *(f32x4*)&Am[i + 4] = hi;
}

extern "C" void kernel_launch(void* const* d_in, const int* in_sizes, int n_in,
                              void* d_out, int out_size, void* d_ws, size_t ws_size,
                              hipStream_t stream) {
  const float* k_in = (const float*)d_in[0];
  const float* v_in = (const float*)d_in[1];
  const float* q_in = (const float*)d_in[2];
  const int* mask = (const int*)d_in[3];
  const float* Wk = (const float*)d_in[4];
  const float* bk = (const float*)d_in[5];
  const float* Wv = (const float*)d_in[6];
  const float* bv = (const float*)d_in[7];
  const float* Wq = (const float*)d_in[8];
  const float* bq = (const float*)d_in[9];
  const float* Wo = (const float*)d_in[10];
  const float* bo = (const float*)d_in[11];

  float* out = (float*)d_out;                       // [8,1024,1024] f32
  float* amean = out + (size_t)8 * 1024 * 1024;     // [8,1024,1024] f32

  u16* ws = (u16*)d_ws;
  u16* WT = ws;
  u16* Xb = ws + 4194304;       // aliases the head of the Pp region (dead later)
  u16* Pp = ws + 4194304;

  // Plan A: 16 planes (one head/block), needs 171966464 u16 = 343,932,928 B.
  // Plan B: 8 planes (head pair/block), needs 104857600 u16 = 209,715,200 B.
  const bool big = ws_size >= (size_t)343932928;
  const int np = big ? 16 : 8;
  const size_t pend = 4194304 + (size_t)np * 8388608;
  u16* Kup  = ws + pend;
  u16* VupT = Kup + 8388608;
  u16* Qup  = VupT + 8388608;
  u16* Ctx  = Qup + 8388608;

  xcvt<<<2048, 256, 0, stream>>>(k_in, v_in, q_in, Xb);
  transpose_w<<<dim3(1024, 4), dim3(256), 0, stream>>>(Wk, Wv, Wq, Wo, WT);
  gemm_qkv<<<dim3(512, 3), dim3(256), 0, stream>>>(
      Xb, WT, bk, bv, bq, Kup, VupT, Qup);
  if (big) {
    attn_kernel<1><<<dim3(8192), dim3(256), 0, stream>>>(
        Qup, Kup, VupT, mask, Ctx, Pp);
  } else {
    attn_kernel<2><<<dim3(4096), dim3(256), 0, stream>>>(
        Qup, Kup, VupT, mask, Ctx, Pp);
  }
  combine<<<4096, 256, 0, stream>>>(Pp, np, amean);
  gemm_out<<<512, 256, 0, stream>>>(Ctx, WT, bo, out);
}

// Round 6
// 595.740 us; speedup vs baseline: 1.0782x; 1.0782x over previous
//
#include <hip/hip_runtime.h>
#include <hip/hip_bf16.h>

typedef unsigned short u16;
typedef unsigned int u32;
typedef __attribute__((ext_vector_type(8))) short bf16x8;
typedef __attribute__((ext_vector_type(4))) float f32x4;
typedef __attribute__((ext_vector_type(4))) u16 u16x4;

#define DEV static __device__ __forceinline__

DEV u16 f2bf(float x) {
  unsigned u = __builtin_bit_cast(unsigned, x);
  u += 0x7fffu + ((u >> 16) & 1u);   // RNE (finite values)
  return (u16)(u >> 16);
}
DEV float bf2f(u16 u) { return __builtin_bit_cast(float, ((unsigned)u) << 16); }

DEV void glds16(const u16* g, u16* l) {
  __builtin_amdgcn_global_load_lds(
      (const __attribute__((address_space(1))) void*)g,
      (__attribute__((address_space(3))) void*)l, 16, 0, 0);
}

// ---- X convert: k,v,q fp32 -> Xb bf16 [3][8388608] (order: k, v, q) ----
__global__ __launch_bounds__(256) void xcvt(
    const float* __restrict__ k, const float* __restrict__ v,
    const float* __restrict__ q, u16* __restrict__ Xb) {
  const size_t i0 = (size_t)blockIdx.x * 256 + threadIdx.x;
  for (size_t t = i0; t < 6291456; t += 524288) {
    const size_t e = t * 4;
    const float* src = (e < 8388608) ? k + e
                     : (e < 16777216) ? v + (e - 8388608)
                     : q + (e - 16777216);
    const f32x4 x = *(const f32x4*)src;
    u16x4 o;
#pragma unroll
    for (int r = 0; r < 4; ++r) o[r] = f2bf(x[r]);
    *(u16x4*)&Xb[e] = o;
  }
}

// ---- transpose+convert weights: out_bf16[n*1024+k] = in_f32[k*1024+n] ----
__global__ __launch_bounds__(256) void transpose_w(
    const float* __restrict__ w0, const float* __restrict__ w1,
    const float* __restrict__ w2, const float* __restrict__ w3,
    u16* __restrict__ out) {
  __shared__ u16 tile[32][33];
  const int mat = blockIdx.y;
  const float* in = (mat == 0) ? w0 : (mat == 1) ? w1 : (mat == 2) ? w2 : w3;
  u16* o = out + (size_t)mat * 1048576;
  const int bk = ((int)blockIdx.x & 31) << 5;
  const int bn = ((int)blockIdx.x >> 5) << 5;
  const int tx = threadIdx.x & 31, ty = threadIdx.x >> 5;
#pragma unroll
  for (int i = 0; i < 32; i += 8)
    tile[ty + i][tx] = f2bf(in[(size_t)(bk + ty + i) * 1024 + bn + tx]);
  __syncthreads();
#pragma unroll
  for (int i = 0; i < 32; i += 8)
    o[(size_t)(bn + ty + i) * 1024 + bk + tx] = tile[tx][ty + i];
}

// ---- m97-style GEMM: 128x128 tile, BK=32, global_load_lds staging ----
// Outputs (fragment-major for attention):
//  mode 0: Kf[bh][T][half][lg][ln][8]  (65536 u16 per bh)
//  mode 1: Vf[bh][wv][kk][lg][ln][8]   (65536 u16 per bh)
//  mode 2: Qup [bh][s][64], scaled 1/8
__global__ __launch_bounds__(256) void gemm_qkv(
    const u16* __restrict__ Xb, const u16* __restrict__ WTall,
    const float* __restrict__ bK, const float* __restrict__ bV,
    const float* __restrict__ bQ,
    u16* __restrict__ Kup, u16* __restrict__ VupT, u16* __restrict__ Qup) {
  __shared__ u16 As[4096];   // [128][32] linear
  __shared__ u16 Bs[4096];
  const int mode = blockIdx.y;
  const u16* A = Xb + (size_t)mode * 8388608;
  const u16* Bw = WTall + (size_t)mode * 1048576;
  const float* bias = (mode == 0) ? bK : (mode == 1) ? bV : bQ;

  const int tid = threadIdx.x;
  const int w = tid >> 6, l = tid & 63;
  const int ln = l & 15, lg = l >> 4, kg8 = lg << 3;
  const int wr = w >> 1, wc = w & 1;
  const int mb = ((int)blockIdx.x >> 3) << 7;
  const int nb = ((int)blockIdx.x & 7) << 7;

  const int srow = (w << 5) + (l >> 2);
  const int sseg = (l & 3) << 3;
  const u16* Ag0 = A + (size_t)(mb + srow) * 1024 + sseg;
  const u16* Bg0 = Bw + (size_t)(nb + srow) * 1024 + sseg;
  u16* Al0 = As + srow * 32 + sseg;
  u16* Bl0 = Bs + srow * 32 + sseg;

  f32x4 acc[4][4] = {};
  const int ar = (wr << 6) + ln;
  const int br = (wc << 6) + ln;

  for (int k0 = 0; k0 < 1024; k0 += 32) {
    glds16(Ag0 + k0, Al0);
    glds16(Ag0 + 16384 + k0, Al0 + 512);
    glds16(Bg0 + k0, Bl0);
    glds16(Bg0 + 16384 + k0, Bl0 + 512);
    __syncthreads();
    bf16x8 aa[4], bb[4];
#pragma unroll
    for (int mt = 0; mt < 4; ++mt) aa[mt] = *(const bf16x8*)&As[(ar + (mt << 4)) * 32 + kg8];
#pragma unroll
    for (int nt = 0; nt < 4; ++nt) bb[nt] = *(const bf16x8*)&Bs[(br + (nt << 4)) * 32 + kg8];
#pragma unroll
    for (int mt = 0; mt < 4; ++mt)
#pragma unroll
      for (int nt = 0; nt < 4; ++nt)
        acc[mt][nt] = __builtin_amdgcn_mfma_f32_16x16x32_bf16(aa[mt], bb[nt], acc[mt][nt], 0, 0, 0);
    __syncthreads();
  }

  const float scale = (mode == 2) ? 0.125f : 1.0f;
#pragma unroll
  for (int mt = 0; mt < 4; ++mt) {
    const int m0 = mb + (wr << 6) + (mt << 4) + (lg << 2);
    const int bb_ = m0 >> 10, s0 = m0 & 1023;
#pragma unroll
    for (int nt = 0; nt < 4; ++nt) {
      const int n = nb + (wc << 6) + (nt << 4) + ln;
      const float bval = bias[n];
      const int h = n >> 6, dh = n & 63;
      const size_t bh = (size_t)(bb_ * 16 + h);
      if (mode == 1) {
        // Vf[bh][wv=dh>>4][kk=s>>5][lgv=(s>>3)&3][lnv=dh&15][e=s&7]
        const int wv = dh >> 4, lnv = dh & 15;
        const int kk = s0 >> 5, lgv = (s0 >> 3) & 3, e0 = s0 & 7;
        u16x4 pk;
#pragma unroll
        for (int r = 0; r < 4; ++r) pk[r] = f2bf(acc[mt][nt][r] + bval);
        *(u16x4*)&VupT[(bh << 16) + (wv << 14) + (kk << 9) + (lgv << 7) +
                       (lnv << 3) + e0] = pk;
      } else if (mode == 0) {
        // Kf[bh][T=s>>4][half=dh>>5][lg2=(dh>>3)&3][ln2=s&15][e=dh&7]
        const int half = dh >> 5, lg2 = (dh >> 3) & 3, e = dh & 7;
        const int T = s0 >> 4;
        u16* base = Kup + (bh << 16) + (T << 10) + (half << 9) + (lg2 << 7) + e;
#pragma unroll
        for (int r = 0; r < 4; ++r)
          base[((s0 & 15) + r) << 3] = f2bf(acc[mt][nt][r] + bval);
      } else {
#pragma unroll
        for (int r = 0; r < 4; ++r)
          Qup[((bh << 10) + s0 + r) * 64 + dh] =
              f2bf((acc[mt][nt][r] + bval) * scale);
      }
    }
  }
}

// ---- out-proj: Out_f32 = Ctx_bf16 @ WoT + bo ----
__global__ __launch_bounds__(256) void gemm_out(
    const u16* __restrict__ Ctx, const u16* __restrict__ WTall,
    const float* __restrict__ bO, float* __restrict__ Out) {
  __shared__ u16 As[4096];
  __shared__ u16 Bs[4096];
  const u16* Bw = WTall + 3145728;

  const int tid = threadIdx.x;
  const int w = tid >> 6, l = tid & 63;
  const int ln = l & 15, lg = l >> 4, kg8 = lg << 3;
  const int wr = w >> 1, wc = w & 1;
  const int mb = ((int)blockIdx.x >> 3) << 7;
  const int nb = ((int)blockIdx.x & 7) << 7;

  const int srow = (w << 5) + (l >> 2);
  const int sseg = (l & 3) << 3;
  const u16* Ag0 = Ctx + (size_t)(mb + srow) * 1024 + sseg;
  const u16* Bg0 = Bw + (size_t)(nb + srow) * 1024 + sseg;
  u16* Al0 = As + srow * 32 + sseg;
  u16* Bl0 = Bs + srow * 32 + sseg;

  f32x4 acc[4][4] = {};
  const int ar = (wr << 6) + ln;
  const int br = (wc << 6) + ln;

  for (int k0 = 0; k0 < 1024; k0 += 32) {
    glds16(Ag0 + k0, Al0);
    glds16(Ag0 + 16384 + k0, Al0 + 512);
    glds16(Bg0 + k0, Bl0);
    glds16(Bg0 + 16384 + k0, Bl0 + 512);
    __syncthreads();
    bf16x8 aa[4], bb[4];
#pragma unroll
    for (int mt = 0; mt < 4; ++mt) aa[mt] = *(const bf16x8*)&As[(ar + (mt << 4)) * 32 + kg8];
#pragma unroll
    for (int nt = 0; nt < 4; ++nt) bb[nt] = *(const bf16x8*)&Bs[(br + (nt << 4)) * 32 + kg8];
#pragma unroll
    for (int mt = 0; mt < 4; ++mt)
#pragma unroll
      for (int nt = 0; nt < 4; ++nt)
        acc[mt][nt] = __builtin_amdgcn_mfma_f32_16x16x32_bf16(aa[mt], bb[nt], acc[mt][nt], 0, 0, 0);
    __syncthreads();
  }
#pragma unroll
  for (int mt = 0; mt < 4; ++mt) {
    const int m0 = mb + (wr << 6) + (mt << 4) + (lg << 2);
#pragma unroll
    for (int nt = 0; nt < 4; ++nt) {
      const int n = nb + (wc << 6) + (nt << 4) + ln;
      const float bval = bO[n];
#pragma unroll
      for (int r = 0; r < 4; ++r)
        Out[(size_t)(m0 + r) * 1024 + n] = acc[mt][nt][r] + bval;
    }
  }
}

// ---- attention: head pair per block, fragment-major K/V (coalesced reads) ----
__global__ __launch_bounds__(256) void attn_kernel(
    const u16* __restrict__ Qup, const u16* __restrict__ Kf,
    const u16* __restrict__ Vf, const int* __restrict__ mask,
    u16* __restrict__ Ctx, u16* __restrict__ Pp) {
  __shared__ u16 P_lds[16 * 1024];   // unnormalized probs, XOR-swizzled rows
  __shared__ float red_m[4][16];
  __shared__ float red_s[4][16];
  __shared__ float invs[16];

  const int tid = threadIdx.x;
  const int w = tid >> 6, l = tid & 63;
  const int ln = l & 15, lg = l >> 4, kg8 = lg << 3;

  // XCD-bijective swizzle: XCD x owns heads {2x,2x+1} for all (b, qtile)
  const int bid = (int)blockIdx.x;
  const int swz = ((bid & 7) << 9) | (bid >> 3);
  const int qb = (swz & 63) << 4;
  const int b = (swz >> 6) & 7;
  const int hs = swz >> 9;           // head pair 0..7

  // mask bits: bit (t*4+r) for (row = 4*lg+r, key = w*256 + t*16 + ln)
  const int* Mp = mask + ((size_t)b << 20) + ((size_t)qb << 10);
  unsigned long long mbits = 0ull;
#pragma unroll
  for (int t = 0; t < 16; ++t) {
    const int key = (w << 8) + (t << 4) + ln;
#pragma unroll
    for (int r = 0; r < 4; ++r) {
      const int row = (lg << 2) + r;
      if (Mp[((size_t)row << 10) + key] != 0) mbits |= 1ull << ((t << 2) + r);
    }
  }

  bf16x8 accv[8];   // bf16 partial plane accumulator (row = tid>>4 layout)

#pragma unroll 1
  for (int hh = 0; hh < 2; ++hh) {
    const int h = (hs << 1) + hh;
    const size_t bh = (size_t)(b * 16 + h);
    const u16* Qp = Qup + ((bh << 10) + qb) * 64;
    const u16* Kb = Kf + (bh << 16);           // fragment-major
    const u16* Vb = Vf + (bh << 16) + ((size_t)w << 14);

    const bf16x8 qa0 = *(const bf16x8*)&Qp[ln * 64 + kg8];
    const bf16x8 qa1 = *(const bf16x8*)&Qp[ln * 64 + 32 + kg8];

    // QK^T: wave w owns key tiles T = w*16 + t; loads are lane-linear 1KB bursts
    f32x4 sc[16];
#pragma unroll
    for (int t = 0; t < 16; ++t) {
      const int Toff = ((w << 4) + t) << 10;
      const bf16x8 kb0 = *(const bf16x8*)&Kb[Toff + (l << 3)];
      const bf16x8 kb1 = *(const bf16x8*)&Kb[Toff + 512 + (l << 3)];
      f32x4 c = {0, 0, 0, 0};
      c = __builtin_amdgcn_mfma_f32_16x16x32_bf16(qa0, kb0, c, 0, 0, 0);
      c = __builtin_amdgcn_mfma_f32_16x16x32_bf16(qa1, kb1, c, 0, 0, 0);
      sc[t] = c;
    }

    // mask + row max
    float rmax[4] = {-3.0e38f, -3.0e38f, -3.0e38f, -3.0e38f};
#pragma unroll
    for (int t = 0; t < 16; ++t)
#pragma unroll
      for (int r = 0; r < 4; ++r) {
        const float s = ((mbits >> ((t << 2) + r)) & 1ull) ? -3.0e38f : sc[t][r];
        sc[t][r] = s;
        rmax[r] = fmaxf(rmax[r], s);
      }
#pragma unroll
    for (int off = 1; off < 16; off <<= 1) {
#pragma unroll
      for (int r = 0; r < 4; ++r) rmax[r] = fmaxf(rmax[r], __shfl_xor(rmax[r], off));
    }
    if (ln == 0) {
#pragma unroll
      for (int r = 0; r < 4; ++r) red_m[w][(lg << 2) + r] = rmax[r];
    }
    __syncthreads();                                   // A: red_m ready
    float mrow[4];
#pragma unroll
    for (int r = 0; r < 4; ++r) {
      const int row = (lg << 2) + r;
      mrow[r] = fmaxf(fmaxf(red_m[0][row], red_m[1][row]),
                      fmaxf(red_m[2][row], red_m[3][row]));
    }
    // exp (unnormalized) + row sum -> red_s (separate buffer, no extra barrier)
    float rsum[4] = {0, 0, 0, 0};
#pragma unroll
    for (int t = 0; t < 16; ++t)
#pragma unroll
      for (int r = 0; r < 4; ++r) {
        const float p = __expf(sc[t][r] - mrow[r]);
        sc[t][r] = p;
        rsum[r] += p;
      }
#pragma unroll
    for (int off = 1; off < 16; off <<= 1) {
#pragma unroll
      for (int r = 0; r < 4; ++r) rsum[r] += __shfl_xor(rsum[r], off);
    }
    if (ln == 0) {
#pragma unroll
      for (int r = 0; r < 4; ++r) red_s[w][(lg << 2) + r] = rsum[r];
    }
    // write unnormalized exp to LDS (bf16, swizzled)
#pragma unroll
    for (int t = 0; t < 16; ++t) {
      const int key = (w << 8) + (t << 4) + ln;
#pragma unroll
      for (int r = 0; r < 4; ++r) {
        const int row = (lg << 2) + r;
        const int bo_ = ((row << 11) + (key << 1)) ^ ((row & 7) << 4);
        *(u16*)((char*)P_lds + bo_) = f2bf(sc[t][r]);
      }
    }
    __syncthreads();                                   // B: red_s + P ready
    float inv[4];
#pragma unroll
    for (int r = 0; r < 4; ++r) {
      const int row = (lg << 2) + r;
      inv[r] = 1.0f / (red_s[0][row] + red_s[1][row] + red_s[2][row] + red_s[3][row]);
    }
    if (w == 0 && ln == 0) {
#pragma unroll
      for (int r = 0; r < 4; ++r) invs[(lg << 2) + r] = inv[r];
    }

    // PV on unnormalized P; V fragments are lane-linear 1KB bursts from Vf.
    f32x4 c0 = {0, 0, 0, 0}, c1 = {0, 0, 0, 0};
#pragma unroll
    for (int kk = 0; kk < 32; kk += 2) {
      const int a0 = ((ln << 11) + (((kk << 5) + kg8) << 1)) ^ ((ln & 7) << 4);
      const int a1 = ((ln << 11) + ((((kk + 1) << 5) + kg8) << 1)) ^ ((ln & 7) << 4);
      const bf16x8 pa0 = *(const bf16x8*)((const char*)P_lds + a0);
      const bf16x8 pa1 = *(const bf16x8*)((const char*)P_lds + a1);
      const bf16x8 vb0 = *(const bf16x8*)&Vb[(kk << 9) + (l << 3)];
      const bf16x8 vb1 = *(const bf16x8*)&Vb[((kk + 1) << 9) + (l << 3)];
      c0 = __builtin_amdgcn_mfma_f32_16x16x32_bf16(pa0, vb0, c0, 0, 0, 0);
      c1 = __builtin_amdgcn_mfma_f32_16x16x32_bf16(pa1, vb1, c1, 0, 0, 0);
    }
    float inv_r[4];
#pragma unroll
    for (int r = 0; r < 4; ++r) {
      const int row = (lg << 2) + r;
      Ctx[(((size_t)b << 10) + qb + row) * 1024 + (h << 6) + (w << 4) + ln] =
          f2bf((c0[r] + c1[r]) * inv[r]);
    }

    // attn_mean plane: readback P_lds * invs[row], coalesced
    {
      const int row = tid >> 4;
      const float iv = invs[row];
      u16* Pg = Pp + ((size_t)hs << 23) + (((size_t)b << 10) + qb + row) * 1024;
#pragma unroll
      for (int i = 0; i < 8; ++i) {
        const int chunk = (tid & 15) + (i << 4);
        const int bo_ = ((row << 11) + (chunk << 4)) ^ ((row & 7) << 4);
        const bf16x8 pv = *(const bf16x8*)((const char*)P_lds + bo_);
        if (hh == 0) {
          bf16x8 o;
#pragma unroll
          for (int e = 0; e < 8; ++e) o[e] = (short)f2bf(bf2f((u16)pv[e]) * iv);
          accv[i] = o;
        } else {
          bf16x8 o;
#pragma unroll
          for (int e = 0; e < 8; ++e)
            o[e] = (short)f2bf(bf2f((u16)accv[i][e]) + bf2f((u16)pv[e]) * iv);
          *(bf16x8*)&Pg[chunk << 3] = o;
        }
      }
    }
    __syncthreads();                                   // C: LDS reuse next head
  }
}

// ---- combine: amean = sum of 8 pair-planes / 16, fp32 out ----
__global__ __launch_bounds__(256) void combine(
    const u16* __restrict__ Pp, float* __restrict__ Am) {
  const size_t i = ((size_t)blockIdx.x * 256 + threadIdx.x) * 8;
  float s[8] = {0, 0, 0, 0, 0, 0, 0, 0};
#pragma unroll
  for (int p = 0; p < 8; ++p) {
    const u16x4* q = (const u16x4*)&Pp[(size_t)p * 8388608 + i];
    const u16x4 a = q[0], c = q[1];
#pragma unroll
    for (int r = 0; r < 4; ++r) { s[r] += bf2f(a[r]); s[r + 4] += bf2f(c[r]); }
  }
  f32x4 lo, hi;
#pragma unroll
  for (int r = 0; r < 4; ++r) { lo[r] = s[r] * 0.0625f; hi[r] = s[r + 4] * 0.0625f; }
  *(f32x4*)&Am[i] = lo;
  *(f32x4*)&Am[i + 4] = hi;
}

extern "C" void kernel_launch(void* const* d_in, const int* in_sizes, int n_in,
                              void* d_out, int out_size, void* d_ws, size_t ws_size,
                              hipStream_t stream) {
  const float* k_in = (const float*)d_in[0];
  const float* v_in = (const float*)d_in[1];
  const float* q_in = (const float*)d_in[2];
  const int* mask = (const int*)d_in[3];
  const float* Wk = (const float*)d_in[4];
  const float* bk = (const float*)d_in[5];
  const float* Wv = (const float*)d_in[6];
  const float* bv = (const float*)d_in[7];
  const float* Wq = (const float*)d_in[8];
  const float* bq = (const float*)d_in[9];
  const float* Wo = (const float*)d_in[10];
  const float* bo = (const float*)d_in[11];

  float* out = (float*)d_out;                       // [8,1024,1024] f32
  float* amean = out + (size_t)8 * 1024 * 1024;     // [8,1024,1024] f32

  // ws layout (u16 units): WT 4M | Pp 8x8M (Xb 24M aliased, dead before attn)
  //  | Kf 8M | Vf 8M | Qup 8M | Ctx 8M  -> 104857600 u16 = 209.7 MB (proven)
  u16* ws = (u16*)d_ws;
  u16* WT = ws;
  u16* Xb = ws + 4194304;
  u16* Pp = ws + 4194304;
  u16* Kf   = ws + 71303168;
  u16* Vf   = ws + 79691776;
  u16* Qup  = ws + 88080384;
  u16* Ctx  = ws + 96468992;

  xcvt<<<2048, 256, 0, stream>>>(k_in, v_in, q_in, Xb);
  transpose_w<<<dim3(1024, 4), dim3(256), 0, stream>>>(Wk, Wv, Wq, Wo, WT);
  gemm_qkv<<<dim3(512, 3), dim3(256), 0, stream>>>(
      Xb, WT, bk, bv, bq, Kf, Vf, Qup);
  attn_kernel<<<dim3(4096), dim3(256), 0, stream>>>(
      Qup, Kf, Vf, mask, Ctx, Pp);
  combine<<<4096, 256, 0, stream>>>(Pp, amean);
  gemm_out<<<512, 256, 0, stream>>>(Ctx, WT, bo, out);
}

// Round 7
// 511.197 us; speedup vs baseline: 1.2565x; 1.1654x over previous
//
#include <hip/hip_runtime.h>
#include <hip/hip_bf16.h>

typedef unsigned short u16;
typedef unsigned int u32;
typedef __attribute__((ext_vector_type(8))) short bf16x8;
typedef __attribute__((ext_vector_type(4))) float f32x4;
typedef __attribute__((ext_vector_type(4))) u16 u16x4;

#define DEV static __device__ __forceinline__

DEV u16 f2bf(float x) {
  unsigned u = __builtin_bit_cast(unsigned, x);
  u += 0x7fffu + ((u >> 16) & 1u);   // RNE (finite values)
  return (u16)(u >> 16);
}
DEV float bf2f(u16 u) { return __builtin_bit_cast(float, ((unsigned)u) << 16); }

DEV void glds16(const u16* g, u16* l) {
  __builtin_amdgcn_global_load_lds(
      (const __attribute__((address_space(1))) void*)g,
      (__attribute__((address_space(3))) void*)l, 16, 0, 0);
}

// ---- X convert: k,v,q fp32 -> Xb bf16 [3][8388608] (order: k, v, q) ----
__global__ __launch_bounds__(256) void xcvt(
    const float* __restrict__ k, const float* __restrict__ v,
    const float* __restrict__ q, u16* __restrict__ Xb) {
  const size_t i0 = (size_t)blockIdx.x * 256 + threadIdx.x;
  for (size_t t = i0; t < 6291456; t += 524288) {
    const size_t e = t * 4;
    const float* src = (e < 8388608) ? k + e
                     : (e < 16777216) ? v + (e - 8388608)
                     : q + (e - 16777216);
    const f32x4 x = *(const f32x4*)src;
    u16x4 o;
#pragma unroll
    for (int r = 0; r < 4; ++r) o[r] = f2bf(x[r]);
    *(u16x4*)&Xb[e] = o;
  }
}

// ---- transpose+convert weights: out_bf16[n*1024+k] = in_f32[k*1024+n] ----
__global__ __launch_bounds__(256) void transpose_w(
    const float* __restrict__ w0, const float* __restrict__ w1,
    const float* __restrict__ w2, const float* __restrict__ w3,
    u16* __restrict__ out) {
  __shared__ u16 tile[32][33];
  const int mat = blockIdx.y;
  const float* in = (mat == 0) ? w0 : (mat == 1) ? w1 : (mat == 2) ? w2 : w3;
  u16* o = out + (size_t)mat * 1048576;
  const int bk = ((int)blockIdx.x & 31) << 5;
  const int bn = ((int)blockIdx.x >> 5) << 5;
  const int tx = threadIdx.x & 31, ty = threadIdx.x >> 5;
#pragma unroll
  for (int i = 0; i < 32; i += 8)
    tile[ty + i][tx] = f2bf(in[(size_t)(bk + ty + i) * 1024 + bn + tx]);
  __syncthreads();
#pragma unroll
  for (int i = 0; i < 32; i += 8)
    o[(size_t)(bn + ty + i) * 1024 + bk + tx] = tile[tx][ty + i];
}

// ---- m97-style GEMM: 128x128 tile, BK=32, global_load_lds staging ----
// Outputs (fragment-major for attention):
//  mode 0: Kf[bh][T][half][lg][ln][8]  (65536 u16 per bh)
//  mode 1: Vf[bh][wv][kk][lg][ln][8]   (65536 u16 per bh)
//  mode 2: Qup [bh][s][64], scaled 1/8
__global__ __launch_bounds__(256) void gemm_qkv(
    const u16* __restrict__ Xb, const u16* __restrict__ WTall,
    const float* __restrict__ bK, const float* __restrict__ bV,
    const float* __restrict__ bQ,
    u16* __restrict__ Kup, u16* __restrict__ VupT, u16* __restrict__ Qup) {
  __shared__ u16 As[4096];   // [128][32] linear
  __shared__ u16 Bs[4096];
  const int mode = blockIdx.y;
  const u16* A = Xb + (size_t)mode * 8388608;
  const u16* Bw = WTall + (size_t)mode * 1048576;
  const float* bias = (mode == 0) ? bK : (mode == 1) ? bV : bQ;

  const int tid = threadIdx.x;
  const int w = tid >> 6, l = tid & 63;
  const int ln = l & 15, lg = l >> 4, kg8 = lg << 3;
  const int wr = w >> 1, wc = w & 1;
  const int mb = ((int)blockIdx.x >> 3) << 7;
  const int nb = ((int)blockIdx.x & 7) << 7;

  const int srow = (w << 5) + (l >> 2);
  const int sseg = (l & 3) << 3;
  const u16* Ag0 = A + (size_t)(mb + srow) * 1024 + sseg;
  const u16* Bg0 = Bw + (size_t)(nb + srow) * 1024 + sseg;
  u16* Al0 = As + srow * 32 + sseg;
  u16* Bl0 = Bs + srow * 32 + sseg;

  f32x4 acc[4][4] = {};
  const int ar = (wr << 6) + ln;
  const int br = (wc << 6) + ln;

  for (int k0 = 0; k0 < 1024; k0 += 32) {
    glds16(Ag0 + k0, Al0);
    glds16(Ag0 + 16384 + k0, Al0 + 512);
    glds16(Bg0 + k0, Bl0);
    glds16(Bg0 + 16384 + k0, Bl0 + 512);
    __syncthreads();
    bf16x8 aa[4], bb[4];
#pragma unroll
    for (int mt = 0; mt < 4; ++mt) aa[mt] = *(const bf16x8*)&As[(ar + (mt << 4)) * 32 + kg8];
#pragma unroll
    for (int nt = 0; nt < 4; ++nt) bb[nt] = *(const bf16x8*)&Bs[(br + (nt << 4)) * 32 + kg8];
#pragma unroll
    for (int mt = 0; mt < 4; ++mt)
#pragma unroll
      for (int nt = 0; nt < 4; ++nt)
        acc[mt][nt] = __builtin_amdgcn_mfma_f32_16x16x32_bf16(aa[mt], bb[nt], acc[mt][nt], 0, 0, 0);
    __syncthreads();
  }

  const float scale = (mode == 2) ? 0.125f : 1.0f;
#pragma unroll
  for (int mt = 0; mt < 4; ++mt) {
    const int m0 = mb + (wr << 6) + (mt << 4) + (lg << 2);
    const int bb_ = m0 >> 10, s0 = m0 & 1023;
#pragma unroll
    for (int nt = 0; nt < 4; ++nt) {
      const int n = nb + (wc << 6) + (nt << 4) + ln;
      const float bval = bias[n];
      const int h = n >> 6, dh = n & 63;
      const size_t bh = (size_t)(bb_ * 16 + h);
      if (mode == 1) {
        // Vf[bh][wv=dh>>4][kk=s>>5][lgv=(s>>3)&3][lnv=dh&15][e=s&7]
        const int wv = dh >> 4, lnv = dh & 15;
        const int kk = s0 >> 5, lgv = (s0 >> 3) & 3, e0 = s0 & 7;
        u16x4 pk;
#pragma unroll
        for (int r = 0; r < 4; ++r) pk[r] = f2bf(acc[mt][nt][r] + bval);
        *(u16x4*)&VupT[(bh << 16) + (wv << 14) + (kk << 9) + (lgv << 7) +
                       (lnv << 3) + e0] = pk;
      } else if (mode == 0) {
        // Kf[bh][T=s>>4][half=dh>>5][lg2=(dh>>3)&3][ln2=s&15][e=dh&7]
        const int half = dh >> 5, lg2 = (dh >> 3) & 3, e = dh & 7;
        const int T = s0 >> 4;
        u16* base = Kup + (bh << 16) + (T << 10) + (half << 9) + (lg2 << 7) + e;
#pragma unroll
        for (int r = 0; r < 4; ++r)
          base[((s0 & 15) + r) << 3] = f2bf(acc[mt][nt][r] + bval);
      } else {
#pragma unroll
        for (int r = 0; r < 4; ++r)
          Qup[((bh << 10) + s0 + r) * 64 + dh] =
              f2bf((acc[mt][nt][r] + bval) * scale);
      }
    }
  }
}

// ---- out-proj: Out_f32 = Ctx_bf16 @ WoT + bo ----
__global__ __launch_bounds__(256) void gemm_out(
    const u16* __restrict__ Ctx, const u16* __restrict__ WTall,
    const float* __restrict__ bO, float* __restrict__ Out) {
  __shared__ u16 As[4096];
  __shared__ u16 Bs[4096];
  const u16* Bw = WTall + 3145728;

  const int tid = threadIdx.x;
  const int w = tid >> 6, l = tid & 63;
  const int ln = l & 15, lg = l >> 4, kg8 = lg << 3;
  const int wr = w >> 1, wc = w & 1;
  const int mb = ((int)blockIdx.x >> 3) << 7;
  const int nb = ((int)blockIdx.x & 7) << 7;

  const int srow = (w << 5) + (l >> 2);
  const int sseg = (l & 3) << 3;
  const u16* Ag0 = Ctx + (size_t)(mb + srow) * 1024 + sseg;
  const u16* Bg0 = Bw + (size_t)(nb + srow) * 1024 + sseg;
  u16* Al0 = As + srow * 32 + sseg;
  u16* Bl0 = Bs + srow * 32 + sseg;

  f32x4 acc[4][4] = {};
  const int ar = (wr << 6) + ln;
  const int br = (wc << 6) + ln;

  for (int k0 = 0; k0 < 1024; k0 += 32) {
    glds16(Ag0 + k0, Al0);
    glds16(Ag0 + 16384 + k0, Al0 + 512);
    glds16(Bg0 + k0, Bl0);
    glds16(Bg0 + 16384 + k0, Bl0 + 512);
    __syncthreads();
    bf16x8 aa[4], bb[4];
#pragma unroll
    for (int mt = 0; mt < 4; ++mt) aa[mt] = *(const bf16x8*)&As[(ar + (mt << 4)) * 32 + kg8];
#pragma unroll
    for (int nt = 0; nt < 4; ++nt) bb[nt] = *(const bf16x8*)&Bs[(br + (nt << 4)) * 32 + kg8];
#pragma unroll
    for (int mt = 0; mt < 4; ++mt)
#pragma unroll
      for (int nt = 0; nt < 4; ++nt)
        acc[mt][nt] = __builtin_amdgcn_mfma_f32_16x16x32_bf16(aa[mt], bb[nt], acc[mt][nt], 0, 0, 0);
    __syncthreads();
  }
#pragma unroll
  for (int mt = 0; mt < 4; ++mt) {
    const int m0 = mb + (wr << 6) + (mt << 4) + (lg << 2);
#pragma unroll
    for (int nt = 0; nt < 4; ++nt) {
      const int n = nb + (wc << 6) + (nt << 4) + ln;
      const float bval = bO[n];
#pragma unroll
      for (int r = 0; r < 4; ++r)
        Out[(size_t)(m0 + r) * 1024 + n] = acc[mt][nt][r] + bval;
    }
  }
}

// ---- attention: fused QK^T+mask+exp (constant shift, no row max) ----
// Register-lean: one f32x4 score tile live at a time -> multi-wave/SIMD.
__global__ __launch_bounds__(256, 2) void attn_kernel(
    const u16* __restrict__ Qup, const u16* __restrict__ Kf,
    const u16* __restrict__ Vf, const int* __restrict__ mask,
    u16* __restrict__ Ctx, u16* __restrict__ Pp) {
  __shared__ u16 P_lds[16 * 1024];   // unnormalized exp(s-4), XOR-swizzled rows
  __shared__ float red_s[4][16];
  __shared__ float invs[16];

  const int tid = threadIdx.x;
  const int w = tid >> 6, l = tid & 63;
  const int ln = l & 15, lg = l >> 4;

  // XCD-bijective swizzle: XCD x owns heads {2x,2x+1} for all (b, qtile)
  const int bid = (int)blockIdx.x;
  const int swz = ((bid & 7) << 9) | (bid >> 3);
  const int qb = (swz & 63) << 4;
  const int b = (swz >> 6) & 7;
  const int hs = swz >> 9;           // head pair 0..7

  // mask bits: bit (t*4+r) for (row = 4*lg+r, key = w*256 + t*16 + ln)
  const int* Mp = mask + ((size_t)b << 20) + ((size_t)qb << 10);
  unsigned long long mbits = 0ull;
#pragma unroll
  for (int t = 0; t < 16; ++t) {
    const int key = (w << 8) + (t << 4) + ln;
#pragma unroll
    for (int r = 0; r < 4; ++r) {
      const int row = (lg << 2) + r;
      if (Mp[((size_t)row << 10) + key] != 0) mbits |= 1ull << ((t << 2) + r);
    }
  }

  bf16x8 accv[8];   // bf16 partial plane accumulator (row = tid>>4 layout)

#pragma unroll 1
  for (int hh = 0; hh < 2; ++hh) {
    const int h = (hs << 1) + hh;
    const size_t bh = (size_t)(b * 16 + h);
    const u16* Qp = Qup + ((bh << 10) + qb) * 64;
    const u16* Kb = Kf + (bh << 16);           // fragment-major
    const u16* Vb = Vf + (bh << 16) + ((size_t)w << 14);

    const bf16x8 qa0 = *(const bf16x8*)&Qp[ln * 64 + (lg << 3)];
    const bf16x8 qa1 = *(const bf16x8*)&Qp[ln * 64 + 32 + (lg << 3)];

    // Fused QK^T -> mask -> exp(s-4) -> LDS; only one score tile live.
    float rsum[4] = {0, 0, 0, 0};
#pragma unroll
    for (int t = 0; t < 16; ++t) {
      const int Toff = ((w << 4) + t) << 10;
      const bf16x8 kb0 = *(const bf16x8*)&Kb[Toff + (l << 3)];
      const bf16x8 kb1 = *(const bf16x8*)&Kb[Toff + 512 + (l << 3)];
      f32x4 c = {0, 0, 0, 0};
      c = __builtin_amdgcn_mfma_f32_16x16x32_bf16(qa0, kb0, c, 0, 0, 0);
      c = __builtin_amdgcn_mfma_f32_16x16x32_bf16(qa1, kb1, c, 0, 0, 0);
      const int key = (w << 8) + (t << 4) + ln;
#pragma unroll
      for (int r = 0; r < 4; ++r) {
        const float p =
            ((mbits >> ((t << 2) + r)) & 1ull) ? 0.0f : __expf(c[r] - 4.0f);
        rsum[r] += p;
        const int row = (lg << 2) + r;
        const int bo_ = ((row << 11) + (key << 1)) ^ ((row & 7) << 4);
        *(u16*)((char*)P_lds + bo_) = f2bf(p);
      }
    }
    // row sums across the 16 ln lanes
#pragma unroll
    for (int off = 1; off < 16; off <<= 1) {
#pragma unroll
      for (int r = 0; r < 4; ++r) rsum[r] += __shfl_xor(rsum[r], off);
    }
    if (ln == 0) {
#pragma unroll
      for (int r = 0; r < 4; ++r) red_s[w][(lg << 2) + r] = rsum[r];
    }
    __syncthreads();                                   // B: P + red_s ready
    float inv[4];
#pragma unroll
    for (int r = 0; r < 4; ++r) {
      const int row = (lg << 2) + r;
      inv[r] = 1.0f / (red_s[0][row] + red_s[1][row] + red_s[2][row] + red_s[3][row]);
    }
    // every wave writes identical invs -> visible to itself without a barrier
    if (ln == 0) {
#pragma unroll
      for (int r = 0; r < 4; ++r) invs[(lg << 2) + r] = inv[r];
    }

    // PV on unnormalized P; V fragments are lane-linear 1KB bursts from Vf.
    f32x4 c0 = {0, 0, 0, 0}, c1 = {0, 0, 0, 0};
    const int kg8 = lg << 3;
#pragma unroll
    for (int kk = 0; kk < 32; kk += 2) {
      const int a0 = ((ln << 11) + (((kk << 5) + kg8) << 1)) ^ ((ln & 7) << 4);
      const int a1 = ((ln << 11) + ((((kk + 1) << 5) + kg8) << 1)) ^ ((ln & 7) << 4);
      const bf16x8 pa0 = *(const bf16x8*)((const char*)P_lds + a0);
      const bf16x8 pa1 = *(const bf16x8*)((const char*)P_lds + a1);
      const bf16x8 vb0 = *(const bf16x8*)&Vb[(kk << 9) + (l << 3)];
      const bf16x8 vb1 = *(const bf16x8*)&Vb[((kk + 1) << 9) + (l << 3)];
      c0 = __builtin_amdgcn_mfma_f32_16x16x32_bf16(pa0, vb0, c0, 0, 0, 0);
      c1 = __builtin_amdgcn_mfma_f32_16x16x32_bf16(pa1, vb1, c1, 0, 0, 0);
    }
#pragma unroll
    for (int r = 0; r < 4; ++r) {
      const int row = (lg << 2) + r;
      Ctx[(((size_t)b << 10) + qb + row) * 1024 + (h << 6) + (w << 4) + ln] =
          f2bf((c0[r] + c1[r]) * inv[r]);
    }

    // attn_mean plane: readback P_lds * invs[row], coalesced
    {
      const int row = tid >> 4;
      const float iv = invs[row];
      u16* Pg = Pp + ((size_t)hs << 23) + (((size_t)b << 10) + qb + row) * 1024;
#pragma unroll
      for (int i = 0; i < 8; ++i) {
        const int chunk = (tid & 15) + (i << 4);
        const int bo_ = ((row << 11) + (chunk << 4)) ^ ((row & 7) << 4);
        const bf16x8 pv = *(const bf16x8*)((const char*)P_lds + bo_);
        if (hh == 0) {
          bf16x8 o;
#pragma unroll
          for (int e = 0; e < 8; ++e) o[e] = (short)f2bf(bf2f((u16)pv[e]) * iv);
          accv[i] = o;
        } else {
          bf16x8 o;
#pragma unroll
          for (int e = 0; e < 8; ++e)
            o[e] = (short)f2bf(bf2f((u16)accv[i][e]) + bf2f((u16)pv[e]) * iv);
          *(bf16x8*)&Pg[chunk << 3] = o;
        }
      }
    }
    __syncthreads();                                   // C: LDS reuse next head
  }
}

// ---- combine: amean = sum of 8 pair-planes / 16, fp32 out ----
__global__ __launch_bounds__(256) void combine(
    const u16* __restrict__ Pp, float* __restrict__ Am) {
  const size_t i = ((size_t)blockIdx.x * 256 + threadIdx.x) * 8;
  float s[8] = {0, 0, 0, 0, 0, 0, 0, 0};
#pragma unroll
  for (int p = 0; p < 8; ++p) {
    const u16x4* q = (const u16x4*)&Pp[(size_t)p * 8388608 + i];
    const u16x4 a = q[0], c = q[1];
#pragma unroll
    for (int r = 0; r < 4; ++r) { s[r] += bf2f(a[r]); s[r + 4] += bf2f(c[r]); }
  }
  f32x4 lo, hi;
#pragma unroll
  for (int r = 0; r < 4; ++r) { lo[r] = s[r] * 0.0625f; hi[r] = s[r + 4] * 0.0625f; }
  *(f32x4*)&Am[i] = lo;
  *(f32x4*)&Am[i + 4] = hi;
}

extern "C" void kernel_launch(void* const* d_in, const int* in_sizes, int n_in,
                              void* d_out, int out_size, void* d_ws, size_t ws_size,
                              hipStream_t stream) {
  const float* k_in = (const float*)d_in[0];
  const float* v_in = (const float*)d_in[1];
  const float* q_in = (const float*)d_in[2];
  const int* mask = (const int*)d_in[3];
  const float* Wk = (const float*)d_in[4];
  const float* bk = (const float*)d_in[5];
  const float* Wv = (const float*)d_in[6];
  const float* bv = (const float*)d_in[7];
  const float* Wq = (const float*)d_in[8];
  const float* bq = (const float*)d_in[9];
  const float* Wo = (const float*)d_in[10];
  const float* bo = (const float*)d_in[11];

  float* out = (float*)d_out;                       // [8,1024,1024] f32
  float* amean = out + (size_t)8 * 1024 * 1024;     // [8,1024,1024] f32

  // ws layout (u16 units): WT 4M | Pp 8x8M (Xb 24M aliased, dead before attn)
  //  | Kf 8M | Vf 8M | Qup 8M | Ctx 8M  -> 104857600 u16 = 209.7 MB (proven)
  u16* ws = (u16*)d_ws;
  u16* WT = ws;
  u16* Xb = ws + 4194304;
  u16* Pp = ws + 4194304;
  u16* Kf   = ws + 71303168;
  u16* Vf   = ws + 79691776;
  u16* Qup  = ws + 88080384;
  u16* Ctx  = ws + 96468992;

  xcvt<<<2048, 256, 0, stream>>>(k_in, v_in, q_in, Xb);
  transpose_w<<<dim3(1024, 4), dim3(256), 0, stream>>>(Wk, Wv, Wq, Wo, WT);
  gemm_qkv<<<dim3(512, 3), dim3(256), 0, stream>>>(
      Xb, WT, bk, bv, bq, Kf, Vf, Qup);
  attn_kernel<<<dim3(4096), dim3(256), 0, stream>>>(
      Qup, Kf, Vf, mask, Ctx, Pp);
  combine<<<4096, 256, 0, stream>>>(Pp, amean);
  gemm_out<<<512, 256, 0, stream>>>(Ctx, WT, bo, out);
}

// Round 9
// 339.779 us; speedup vs baseline: 1.8905x; 1.5045x over previous
//
#include <hip/hip_runtime.h>
#include <hip/hip_bf16.h>

typedef unsigned short u16;
typedef unsigned int u32;
typedef __attribute__((ext_vector_type(8))) short bf16x8;
typedef __attribute__((ext_vector_type(4))) float f32x4;
typedef __attribute__((ext_vector_type(4))) u16 u16x4;

#define DEV static __device__ __forceinline__

DEV u16 f2bf(float x) {
  unsigned u = __builtin_bit_cast(unsigned, x);
  u += 0x7fffu + ((u >> 16) & 1u);   // RNE (finite values)
  return (u16)(u >> 16);
}
DEV float bf2f(u16 u) { return __builtin_bit_cast(float, ((unsigned)u) << 16); }

DEV void glds16(const u16* g, u16* l) {
  __builtin_amdgcn_global_load_lds(
      (const __attribute__((address_space(1))) void*)g,
      (__attribute__((address_space(3))) void*)l, 16, 0, 0);
}

// ---- X convert: k,v,q fp32 -> Xb bf16 [3][8388608] (order: k, v, q) ----
__global__ __launch_bounds__(256) void xcvt(
    const float* __restrict__ k, const float* __restrict__ v,
    const float* __restrict__ q, u16* __restrict__ Xb) {
  const size_t i0 = (size_t)blockIdx.x * 256 + threadIdx.x;
  for (size_t t = i0; t < 6291456; t += 524288) {
    const size_t e = t * 4;
    const float* src = (e < 8388608) ? k + e
                     : (e < 16777216) ? v + (e - 8388608)
                     : q + (e - 16777216);
    const f32x4 x = *(const f32x4*)src;
    u16x4 o;
#pragma unroll
    for (int r = 0; r < 4; ++r) o[r] = f2bf(x[r]);
    *(u16x4*)&Xb[e] = o;
  }
}

// ---- transpose+convert weights: out_bf16[n*1024+k] = in_f32[k*1024+n] ----
__global__ __launch_bounds__(256) void transpose_w(
    const float* __restrict__ w0, const float* __restrict__ w1,
    const float* __restrict__ w2, const float* __restrict__ w3,
    u16* __restrict__ out) {
  __shared__ u16 tile[32][33];
  const int mat = blockIdx.y;
  const float* in = (mat == 0) ? w0 : (mat == 1) ? w1 : (mat == 2) ? w2 : w3;
  u16* o = out + (size_t)mat * 1048576;
  const int bk = ((int)blockIdx.x & 31) << 5;
  const int bn = ((int)blockIdx.x >> 5) << 5;
  const int tx = threadIdx.x & 31, ty = threadIdx.x >> 5;
#pragma unroll
  for (int i = 0; i < 32; i += 8)
    tile[ty + i][tx] = f2bf(in[(size_t)(bk + ty + i) * 1024 + bn + tx]);
  __syncthreads();
#pragma unroll
  for (int i = 0; i < 32; i += 8)
    o[(size_t)(bn + ty + i) * 1024 + bk + tx] = tile[tx][ty + i];
}

// ---- m97-style GEMM: 128x128 tile, BK=32, global_load_lds staging ----
// Outputs (fragment-major for attention):
//  mode 0: Kf[bh][T][half][lg][ln][8]  (65536 u16 per bh)
//  mode 1: Vf[bh][wv][kk][lg][ln][8]   (65536 u16 per bh)
//  mode 2: Qup [bh][s][64], scaled 1/8
__global__ __launch_bounds__(256) void gemm_qkv(
    const u16* __restrict__ Xb, const u16* __restrict__ WTall,
    const float* __restrict__ bK, const float* __restrict__ bV,
    const float* __restrict__ bQ,
    u16* __restrict__ Kup, u16* __restrict__ VupT, u16* __restrict__ Qup) {
  __shared__ u16 As[4096];   // [128][32] linear
  __shared__ u16 Bs[4096];
  const int mode = blockIdx.y;
  const u16* A = Xb + (size_t)mode * 8388608;
  const u16* Bw = WTall + (size_t)mode * 1048576;
  const float* bias = (mode == 0) ? bK : (mode == 1) ? bV : bQ;

  const int tid = threadIdx.x;
  const int w = tid >> 6, l = tid & 63;
  const int ln = l & 15, lg = l >> 4, kg8 = lg << 3;
  const int wr = w >> 1, wc = w & 1;
  const int mb = ((int)blockIdx.x >> 3) << 7;
  const int nb = ((int)blockIdx.x & 7) << 7;

  const int srow = (w << 5) + (l >> 2);
  const int sseg = (l & 3) << 3;
  const u16* Ag0 = A + (size_t)(mb + srow) * 1024 + sseg;
  const u16* Bg0 = Bw + (size_t)(nb + srow) * 1024 + sseg;
  u16* Al0 = As + srow * 32 + sseg;
  u16* Bl0 = Bs + srow * 32 + sseg;

  f32x4 acc[4][4] = {};
  const int ar = (wr << 6) + ln;
  const int br = (wc << 6) + ln;

  for (int k0 = 0; k0 < 1024; k0 += 32) {
    glds16(Ag0 + k0, Al0);
    glds16(Ag0 + 16384 + k0, Al0 + 512);
    glds16(Bg0 + k0, Bl0);
    glds16(Bg0 + 16384 + k0, Bl0 + 512);
    __syncthreads();
    bf16x8 aa[4], bb[4];
#pragma unroll
    for (int mt = 0; mt < 4; ++mt) aa[mt] = *(const bf16x8*)&As[(ar + (mt << 4)) * 32 + kg8];
#pragma unroll
    for (int nt = 0; nt < 4; ++nt) bb[nt] = *(const bf16x8*)&Bs[(br + (nt << 4)) * 32 + kg8];
#pragma unroll
    for (int mt = 0; mt < 4; ++mt)
#pragma unroll
      for (int nt = 0; nt < 4; ++nt)
        acc[mt][nt] = __builtin_amdgcn_mfma_f32_16x16x32_bf16(aa[mt], bb[nt], acc[mt][nt], 0, 0, 0);
    __syncthreads();
  }

  const float scale = (mode == 2) ? 0.125f : 1.0f;
#pragma unroll
  for (int mt = 0; mt < 4; ++mt) {
    const int m0 = mb + (wr << 6) + (mt << 4) + (lg << 2);
    const int bb_ = m0 >> 10, s0 = m0 & 1023;
#pragma unroll
    for (int nt = 0; nt < 4; ++nt) {
      const int n = nb + (wc << 6) + (nt << 4) + ln;
      const float bval = bias[n];
      const int h = n >> 6, dh = n & 63;
      const size_t bh = (size_t)(bb_ * 16 + h);
      if (mode == 1) {
        // Vf[bh][wv=dh>>4][kk=s>>5][lgv=(s>>3)&3][lnv=dh&15][e=s&7]
        const int wv = dh >> 4, lnv = dh & 15;
        const int kk = s0 >> 5, lgv = (s0 >> 3) & 3, e0 = s0 & 7;
        u16x4 pk;
#pragma unroll
        for (int r = 0; r < 4; ++r) pk[r] = f2bf(acc[mt][nt][r] + bval);
        *(u16x4*)&VupT[(bh << 16) + (wv << 14) + (kk << 9) + (lgv << 7) +
                       (lnv << 3) + e0] = pk;
      } else if (mode == 0) {
        // Kf[bh][T=s>>4][half=dh>>5][lg2=(dh>>3)&3][ln2=s&15][e=dh&7]
        const int half = dh >> 5, lg2 = (dh >> 3) & 3, e = dh & 7;
        const int T = s0 >> 4;
        u16* base = Kup + (bh << 16) + (T << 10) + (half << 9) + (lg2 << 7) + e;
#pragma unroll
        for (int r = 0; r < 4; ++r)
          base[((s0 & 15) + r) << 3] = f2bf(acc[mt][nt][r] + bval);
      } else {
#pragma unroll
        for (int r = 0; r < 4; ++r)
          Qup[((bh << 10) + s0 + r) * 64 + dh] =
              f2bf((acc[mt][nt][r] + bval) * scale);
      }
    }
  }
}

// ---- out-proj: Out_f32 = Ctx_bf16 @ WoT + bo ----
__global__ __launch_bounds__(256) void gemm_out(
    const u16* __restrict__ Ctx, const u16* __restrict__ WTall,
    const float* __restrict__ bO, float* __restrict__ Out) {
  __shared__ u16 As[4096];
  __shared__ u16 Bs[4096];
  const u16* Bw = WTall + 3145728;

  const int tid = threadIdx.x;
  const int w = tid >> 6, l = tid & 63;
  const int ln = l & 15, lg = l >> 4, kg8 = lg << 3;
  const int wr = w >> 1, wc = w & 1;
  const int mb = ((int)blockIdx.x >> 3) << 7;
  const int nb = ((int)blockIdx.x & 7) << 7;

  const int srow = (w << 5) + (l >> 2);
  const int sseg = (l & 3) << 3;
  const u16* Ag0 = Ctx + (size_t)(mb + srow) * 1024 + sseg;
  const u16* Bg0 = Bw + (size_t)(nb + srow) * 1024 + sseg;
  u16* Al0 = As + srow * 32 + sseg;
  u16* Bl0 = Bs + srow * 32 + sseg;

  f32x4 acc[4][4] = {};
  const int ar = (wr << 6) + ln;
  const int br = (wc << 6) + ln;

  for (int k0 = 0; k0 < 1024; k0 += 32) {
    glds16(Ag0 + k0, Al0);
    glds16(Ag0 + 16384 + k0, Al0 + 512);
    glds16(Bg0 + k0, Bl0);
    glds16(Bg0 + 16384 + k0, Bl0 + 512);
    __syncthreads();
    bf16x8 aa[4], bb[4];
#pragma unroll
    for (int mt = 0; mt < 4; ++mt) aa[mt] = *(const bf16x8*)&As[(ar + (mt << 4)) * 32 + kg8];
#pragma unroll
    for (int nt = 0; nt < 4; ++nt) bb[nt] = *(const bf16x8*)&Bs[(br + (nt << 4)) * 32 + kg8];
#pragma unroll
    for (int mt = 0; mt < 4; ++mt)
#pragma unroll
      for (int nt = 0; nt < 4; ++nt)
        acc[mt][nt] = __builtin_amdgcn_mfma_f32_16x16x32_bf16(aa[mt], bb[nt], acc[mt][nt], 0, 0, 0);
    __syncthreads();
  }
#pragma unroll
  for (int mt = 0; mt < 4; ++mt) {
    const int m0 = mb + (wr << 6) + (mt << 4) + (lg << 2);
#pragma unroll
    for (int nt = 0; nt < 4; ++nt) {
      const int n = nb + (wc << 6) + (nt << 4) + ln;
      const float bval = bO[n];
#pragma unroll
      for (int r = 0; r < 4; ++r)
        Out[(size_t)(m0 + r) * 1024 + n] = acc[mt][nt][r] + bval;
    }
  }
}

// ---- attention: fused exp + register-rotating K/V prefetch (depth 3 / 4) ----
__global__ __launch_bounds__(256, 2) void attn_kernel(
    const u16* __restrict__ Qup, const u16* __restrict__ Kf,
    const u16* __restrict__ Vf, const int* __restrict__ mask,
    u16* __restrict__ Ctx, u16* __restrict__ Pp) {
  __shared__ u16 P_lds[16 * 1024];   // unnormalized exp(s-4), XOR-swizzled rows
  __shared__ float red_s[4][16];
  __shared__ float invs[16];

  const int tid = threadIdx.x;
  const int w = tid >> 6, l = tid & 63;
  const int ln = l & 15, lg = l >> 4;
  const int kg8 = lg << 3;

  // XCD-bijective swizzle: XCD x owns heads {2x,2x+1} for all (b, qtile)
  const int bid = (int)blockIdx.x;
  const int swz = ((bid & 7) << 9) | (bid >> 3);
  const int qb = (swz & 63) << 4;
  const int b = (swz >> 6) & 7;
  const int hs = swz >> 9;           // head pair 0..7

  // mask bits: bit (t*4+r) for (row = 4*lg+r, key = w*256 + t*16 + ln)
  const int* Mp = mask + ((size_t)b << 20) + ((size_t)qb << 10);
  unsigned long long mbits = 0ull;
#pragma unroll
  for (int t = 0; t < 16; ++t) {
    const int key = (w << 8) + (t << 4) + ln;
#pragma unroll
    for (int r = 0; r < 4; ++r) {
      const int row = (lg << 2) + r;
      if (Mp[((size_t)row << 10) + key] != 0) mbits |= 1ull << ((t << 2) + r);
    }
  }

  bf16x8 accv[8];   // bf16 partial plane accumulator (row = tid>>4 layout)

#pragma unroll 1
  for (int hh = 0; hh < 2; ++hh) {
    const int h = (hs << 1) + hh;
    const size_t bh = (size_t)(b * 16 + h);
    const u16* Qp = Qup + ((bh << 10) + qb) * 64;
    const u16* Kb = Kf + (bh << 16);                     // fragment-major
    const u16* Vb = Vf + (bh << 16) + ((size_t)w << 14);

    const bf16x8 qa0 = *(const bf16x8*)&Qp[ln * 64 + kg8];
    const bf16x8 qa1 = *(const bf16x8*)&Qp[ln * 64 + 32 + kg8];

    // K register pipeline, depth 3 (static rotation -> stays in VGPRs)
    bf16x8 ka[3], kb[3];
#pragma unroll
    for (int p = 0; p < 3; ++p) {
      const int To = ((w << 4) + p) << 10;
      ka[p] = *(const bf16x8*)&Kb[To + (l << 3)];
      kb[p] = *(const bf16x8*)&Kb[To + 512 + (l << 3)];
    }

    // Fused QK^T -> mask -> exp(s-4) -> P_lds
    float rsum[4] = {0, 0, 0, 0};
#pragma unroll
    for (int t = 0; t < 16; ++t) {
      const int s = t % 3;                 // constant after unroll
      const bf16x8 k0 = ka[s], k1 = kb[s];
      if (t + 3 < 16) {                    // prefetch 3 tiles ahead
        const int To = ((w << 4) + t + 3) << 10;
        ka[s] = *(const bf16x8*)&Kb[To + (l << 3)];
        kb[s] = *(const bf16x8*)&Kb[To + 512 + (l << 3)];
      }
      f32x4 c = {0, 0, 0, 0};
      c = __builtin_amdgcn_mfma_f32_16x16x32_bf16(qa0, k0, c, 0, 0, 0);
      c = __builtin_amdgcn_mfma_f32_16x16x32_bf16(qa1, k1, c, 0, 0, 0);
      const int key = (w << 8) + (t << 4) + ln;
#pragma unroll
      for (int r = 0; r < 4; ++r) {
        const float p =
            ((mbits >> ((t << 2) + r)) & 1ull) ? 0.0f : __expf(c[r] - 4.0f);
        rsum[r] += p;
        const int row = (lg << 2) + r;
        const int bo_ = ((row << 11) + (key << 1)) ^ ((row & 7) << 4);
        *(u16*)((char*)P_lds + bo_) = f2bf(p);
      }
    }
    // row sums across the 16 ln lanes
#pragma unroll
    for (int off = 1; off < 16; off <<= 1) {
#pragma unroll
      for (int r = 0; r < 4; ++r) rsum[r] += __shfl_xor(rsum[r], off);
    }
    if (ln == 0) {
#pragma unroll
      for (int r = 0; r < 4; ++r) red_s[w][(lg << 2) + r] = rsum[r];
    }

    // V register pipeline, depth 4; prologue overlaps the barrier wait
    bf16x8 vr[4];
#pragma unroll
    for (int p = 0; p < 4; ++p)
      vr[p] = *(const bf16x8*)&Vb[(p << 9) + (l << 3)];

    __syncthreads();                                   // P + red_s ready
    float inv[4];
#pragma unroll
    for (int r = 0; r < 4; ++r) {
      const int row = (lg << 2) + r;
      inv[r] = 1.0f / (red_s[0][row] + red_s[1][row] + red_s[2][row] + red_s[3][row]);
    }
    if (ln == 0) {
#pragma unroll
      for (int r = 0; r < 4; ++r) invs[(lg << 2) + r] = inv[r];
    }

    // PV on unnormalized P; V prefetched 4 tiles ahead in registers.
    f32x4 c0 = {0, 0, 0, 0}, c1 = {0, 0, 0, 0};
#pragma unroll
    for (int kk = 0; kk < 32; ++kk) {
      const int s = kk & 3;
      const bf16x8 vb = vr[s];
      if (kk + 4 < 32)
        vr[s] = *(const bf16x8*)&Vb[((kk + 4) << 9) + (l << 3)];
      const int a0 = ((ln << 11) + (((kk << 5) + kg8) << 1)) ^ ((ln & 7) << 4);
      const bf16x8 pa = *(const bf16x8*)((const char*)P_lds + a0);
      if (kk & 1)
        c1 = __builtin_amdgcn_mfma_f32_16x16x32_bf16(pa, vb, c1, 0, 0, 0);
      else
        c0 = __builtin_amdgcn_mfma_f32_16x16x32_bf16(pa, vb, c0, 0, 0, 0);
    }
#pragma unroll
    for (int r = 0; r < 4; ++r) {
      const int row = (lg << 2) + r;
      Ctx[(((size_t)b << 10) + qb + row) * 1024 + (h << 6) + (w << 4) + ln] =
          f2bf((c0[r] + c1[r]) * inv[r]);
    }

    // attn_mean plane: readback P_lds * invs[row], coalesced
    {
      const int row = tid >> 4;
      const float iv = invs[row];
      u16* Pg = Pp + ((size_t)hs << 23) + (((size_t)b << 10) + qb + row) * 1024;
#pragma unroll
      for (int i = 0; i < 8; ++i) {
        const int chunk = (tid & 15) + (i << 4);
        const int bo_ = ((row << 11) + (chunk << 4)) ^ ((row & 7) << 4);
        const bf16x8 pv = *(const bf16x8*)((const char*)P_lds + bo_);
        if (hh == 0) {
          bf16x8 o;
#pragma unroll
          for (int e = 0; e < 8; ++e) o[e] = (short)f2bf(bf2f((u16)pv[e]) * iv);
          accv[i] = o;
        } else {
          bf16x8 o;
#pragma unroll
          for (int e = 0; e < 8; ++e)
            o[e] = (short)f2bf(bf2f((u16)accv[i][e]) + bf2f((u16)pv[e]) * iv);
          *(bf16x8*)&Pg[chunk << 3] = o;
        }
      }
    }
    __syncthreads();                                   // LDS reuse next head
  }
}

// ---- combine: amean = sum of 8 pair-planes / 16, fp32 out ----
__global__ __launch_bounds__(256) void combine(
    const u16* __restrict__ Pp, float* __restrict__ Am) {
  const size_t i = ((size_t)blockIdx.x * 256 + threadIdx.x) * 8;
  float s[8] = {0, 0, 0, 0, 0, 0, 0, 0};
#pragma unroll
  for (int p = 0; p < 8; ++p) {
    const u16x4* q = (const u16x4*)&Pp[(size_t)p * 8388608 + i];
    const u16x4 a = q[0], c = q[1];
#pragma unroll
    for (int r = 0; r < 4; ++r) { s[r] += bf2f(a[r]); s[r + 4] += bf2f(c[r]); }
  }
  f32x4 lo, hi;
#pragma unroll
  for (int r = 0; r < 4; ++r) { lo[r] = s[r] * 0.0625f; hi[r] = s[r + 4] * 0.0625f; }
  *(f32x4*)&Am[i] = lo;
  *(f32x4*)&Am[i + 4] = hi;
}

extern "C" void kernel_launch(void* const* d_in, const int* in_sizes, int n_in,
                              void* d_out, int out_size, void* d_ws, size_t ws_size,
                              hipStream_t stream) {
  const float* k_in = (const float*)d_in[0];
  const float* v_in = (const float*)d_in[1];
  const float* q_in = (const float*)d_in[2];
  const int* mask = (const int*)d_in[3];
  const float* Wk = (const float*)d_in[4];
  const float* bk = (const float*)d_in[5];
  const float* Wv = (const float*)d_in[6];
  const float* bv = (const float*)d_in[7];
  const float* Wq = (const float*)d_in[8];
  const float* bq = (const float*)d_in[9];
  const float* Wo = (const float*)d_in[10];
  const float* bo = (const float*)d_in[11];

  float* out = (float*)d_out;                       // [8,1024,1024] f32
  float* amean = out + (size_t)8 * 1024 * 1024;     // [8,1024,1024] f32

  // ws layout (u16 units): WT 4M | Pp 8x8M (Xb 24M aliased, dead before attn)
  //  | Kf 8M | Vf 8M | Qup 8M | Ctx 8M  -> 104857600 u16 = 209.7 MB (proven)
  u16* ws = (u16*)d_ws;
  u16* WT = ws;
  u16* Xb = ws + 4194304;
  u16* Pp = ws + 4194304;
  u16* Kf   = ws + 71303168;
  u16* Vf   = ws + 79691776;
  u16* Qup  = ws + 88080384;
  u16* Ctx  = ws + 96468992;

  xcvt<<<2048, 256, 0, stream>>>(k_in, v_in, q_in, Xb);
  transpose_w<<<dim3(1024, 4), dim3(256), 0, stream>>>(Wk, Wv, Wq, Wo, WT);
  gemm_qkv<<<dim3(512, 3), dim3(256), 0, stream>>>(
      Xb, WT, bk, bv, bq, Kf, Vf, Qup);
  attn_kernel<<<dim3(4096), dim3(256), 0, stream>>>(
      Qup, Kf, Vf, mask, Ctx, Pp);
  combine<<<4096, 256, 0, stream>>>(Pp, amean);
  gemm_out<<<512, 256, 0, stream>>>(Ctx, WT, bo, out);
}

// Round 10
// 311.856 us; speedup vs baseline: 2.0597x; 1.0895x over previous
//
#include <hip/hip_runtime.h>
#include <hip/hip_bf16.h>

typedef unsigned short u16;
typedef unsigned int u32;
typedef __attribute__((ext_vector_type(8))) short bf16x8;
typedef __attribute__((ext_vector_type(4))) float f32x4;
typedef __attribute__((ext_vector_type(4))) u16 u16x4;
typedef __attribute__((ext_vector_type(4))) u32 u32x4;

#define DEV static __device__ __forceinline__

DEV u16 f2bf(float x) {
  unsigned u = __builtin_bit_cast(unsigned, x);
  u += 0x7fffu + ((u >> 16) & 1u);   // RNE (finite values)
  return (u16)(u >> 16);
}
DEV float bf2f(u16 u) { return __builtin_bit_cast(float, ((unsigned)u) << 16); }

DEV u32 cvtpk(float lo, float hi) {   // packed f32->bf16 (RNE), gfx950
  u32 r;
  asm("v_cvt_pk_bf16_f32 %0, %1, %2" : "=v"(r) : "v"(lo), "v"(hi));
  return r;
}

DEV void glds16(const u16* g, u16* l) {
  __builtin_amdgcn_global_load_lds(
      (const __attribute__((address_space(1))) void*)g,
      (__attribute__((address_space(3))) void*)l, 16, 0, 0);
}

// ---- X convert: k,v,q fp32 -> Xb bf16 [3][8388608] (order: k, v, q) ----
__global__ __launch_bounds__(256) void xcvt(
    const float* __restrict__ k, const float* __restrict__ v,
    const float* __restrict__ q, u16* __restrict__ Xb) {
  const size_t i0 = (size_t)blockIdx.x * 256 + threadIdx.x;
  for (size_t t = i0; t < 6291456; t += 524288) {
    const size_t e = t * 4;
    const float* src = (e < 8388608) ? k + e
                     : (e < 16777216) ? v + (e - 8388608)
                     : q + (e - 16777216);
    const f32x4 x = *(const f32x4*)src;
    u16x4 o;
#pragma unroll
    for (int r = 0; r < 4; ++r) o[r] = f2bf(x[r]);
    *(u16x4*)&Xb[e] = o;
  }
}

// ---- transpose+convert weights: out_bf16[n*1024+k] = in_f32[k*1024+n] ----
__global__ __launch_bounds__(256) void transpose_w(
    const float* __restrict__ w0, const float* __restrict__ w1,
    const float* __restrict__ w2, const float* __restrict__ w3,
    u16* __restrict__ out) {
  __shared__ u16 tile[32][33];
  const int mat = blockIdx.y;
  const float* in = (mat == 0) ? w0 : (mat == 1) ? w1 : (mat == 2) ? w2 : w3;
  u16* o = out + (size_t)mat * 1048576;
  const int bk = ((int)blockIdx.x & 31) << 5;
  const int bn = ((int)blockIdx.x >> 5) << 5;
  const int tx = threadIdx.x & 31, ty = threadIdx.x >> 5;
#pragma unroll
  for (int i = 0; i < 32; i += 8)
    tile[ty + i][tx] = f2bf(in[(size_t)(bk + ty + i) * 1024 + bn + tx]);
  __syncthreads();
#pragma unroll
  for (int i = 0; i < 32; i += 8)
    o[(size_t)(bn + ty + i) * 1024 + bk + tx] = tile[tx][ty + i];
}

// ---- maskpack: per-(b,qtile,lane) 64-bit mask word, matching attn's layout ----
// bit (t*4+r) for (row = 4*(l>>4)+r, key = (tid>>6)*256 + t*16 + (l&15))
__global__ __launch_bounds__(256) void maskpack(
    const int* __restrict__ mask, unsigned long long* __restrict__ Mb) {
  const int qt = blockIdx.x, b = blockIdx.y;
  const int tid = threadIdx.x;
  const int w = tid >> 6, l = tid & 63;
  const int ln = l & 15, lg = l >> 4;
  const int* Mp = mask + ((size_t)b << 20) + ((size_t)(qt << 4) << 10);
  unsigned long long m = 0ull;
#pragma unroll
  for (int t = 0; t < 16; ++t) {
    const int key = (w << 8) + (t << 4) + ln;
#pragma unroll
    for (int r = 0; r < 4; ++r) {
      const int row = (lg << 2) + r;
      if (Mp[((size_t)row << 10) + key] != 0) m |= 1ull << ((t << 2) + r);
    }
  }
  Mb[((((size_t)b << 6) + qt) << 8) + tid] = m;
}

// ---- m97-style GEMM: 128x128 tile, BK=32, global_load_lds staging ----
// Outputs (fragment-major for attention):
//  mode 0: Kf[bh][T][half][lg][ln][8]  (65536 u16 per bh)
//  mode 1: Vf[bh][wv][kk][lg][ln][8]   (65536 u16 per bh)
//  mode 2: Qup [bh][s][64], scaled 1/8
__global__ __launch_bounds__(256) void gemm_qkv(
    const u16* __restrict__ Xb, const u16* __restrict__ WTall,
    const float* __restrict__ bK, const float* __restrict__ bV,
    const float* __restrict__ bQ,
    u16* __restrict__ Kup, u16* __restrict__ VupT, u16* __restrict__ Qup) {
  __shared__ u16 As[4096];   // [128][32] linear
  __shared__ u16 Bs[4096];
  const int mode = blockIdx.y;
  const u16* A = Xb + (size_t)mode * 8388608;
  const u16* Bw = WTall + (size_t)mode * 1048576;
  const float* bias = (mode == 0) ? bK : (mode == 1) ? bV : bQ;

  const int tid = threadIdx.x;
  const int w = tid >> 6, l = tid & 63;
  const int ln = l & 15, lg = l >> 4, kg8 = lg << 3;
  const int wr = w >> 1, wc = w & 1;
  const int mb = ((int)blockIdx.x >> 3) << 7;
  const int nb = ((int)blockIdx.x & 7) << 7;

  const int srow = (w << 5) + (l >> 2);
  const int sseg = (l & 3) << 3;
  const u16* Ag0 = A + (size_t)(mb + srow) * 1024 + sseg;
  const u16* Bg0 = Bw + (size_t)(nb + srow) * 1024 + sseg;
  u16* Al0 = As + srow * 32 + sseg;
  u16* Bl0 = Bs + srow * 32 + sseg;

  f32x4 acc[4][4] = {};
  const int ar = (wr << 6) + ln;
  const int br = (wc << 6) + ln;

  for (int k0 = 0; k0 < 1024; k0 += 32) {
    glds16(Ag0 + k0, Al0);
    glds16(Ag0 + 16384 + k0, Al0 + 512);
    glds16(Bg0 + k0, Bl0);
    glds16(Bg0 + 16384 + k0, Bl0 + 512);
    __syncthreads();
    bf16x8 aa[4], bb[4];
#pragma unroll
    for (int mt = 0; mt < 4; ++mt) aa[mt] = *(const bf16x8*)&As[(ar + (mt << 4)) * 32 + kg8];
#pragma unroll
    for (int nt = 0; nt < 4; ++nt) bb[nt] = *(const bf16x8*)&Bs[(br + (nt << 4)) * 32 + kg8];
#pragma unroll
    for (int mt = 0; mt < 4; ++mt)
#pragma unroll
      for (int nt = 0; nt < 4; ++nt)
        acc[mt][nt] = __builtin_amdgcn_mfma_f32_16x16x32_bf16(aa[mt], bb[nt], acc[mt][nt], 0, 0, 0);
    __syncthreads();
  }

  const float scale = (mode == 2) ? 0.125f : 1.0f;
#pragma unroll
  for (int mt = 0; mt < 4; ++mt) {
    const int m0 = mb + (wr << 6) + (mt << 4) + (lg << 2);
    const int bb_ = m0 >> 10, s0 = m0 & 1023;
#pragma unroll
    for (int nt = 0; nt < 4; ++nt) {
      const int n = nb + (wc << 6) + (nt << 4) + ln;
      const float bval = bias[n];
      const int h = n >> 6, dh = n & 63;
      const size_t bh = (size_t)(bb_ * 16 + h);
      if (mode == 1) {
        // Vf[bh][wv=dh>>4][kk=s>>5][lgv=(s>>3)&3][lnv=dh&15][e=s&7]
        const int wv = dh >> 4, lnv = dh & 15;
        const int kk = s0 >> 5, lgv = (s0 >> 3) & 3, e0 = s0 & 7;
        u16x4 pk;
#pragma unroll
        for (int r = 0; r < 4; ++r) pk[r] = f2bf(acc[mt][nt][r] + bval);
        *(u16x4*)&VupT[(bh << 16) + (wv << 14) + (kk << 9) + (lgv << 7) +
                       (lnv << 3) + e0] = pk;
      } else if (mode == 0) {
        // Kf[bh][T=s>>4][half=dh>>5][lg2=(dh>>3)&3][ln2=s&15][e=dh&7]
        const int half = dh >> 5, lg2 = (dh >> 3) & 3, e = dh & 7;
        const int T = s0 >> 4;
        u16* base = Kup + (bh << 16) + (T << 10) + (half << 9) + (lg2 << 7) + e;
#pragma unroll
        for (int r = 0; r < 4; ++r)
          base[((s0 & 15) + r) << 3] = f2bf(acc[mt][nt][r] + bval);
      } else {
#pragma unroll
        for (int r = 0; r < 4; ++r)
          Qup[((bh << 10) + s0 + r) * 64 + dh] =
              f2bf((acc[mt][nt][r] + bval) * scale);
      }
    }
  }
}

// ---- out-proj: Out_f32 = Ctx_bf16 @ WoT + bo ----
__global__ __launch_bounds__(256) void gemm_out(
    const u16* __restrict__ Ctx, const u16* __restrict__ WTall,
    const float* __restrict__ bO, float* __restrict__ Out) {
  __shared__ u16 As[4096];
  __shared__ u16 Bs[4096];
  const u16* Bw = WTall + 3145728;

  const int tid = threadIdx.x;
  const int w = tid >> 6, l = tid & 63;
  const int ln = l & 15, lg = l >> 4, kg8 = lg << 3;
  const int wr = w >> 1, wc = w & 1;
  const int mb = ((int)blockIdx.x >> 3) << 7;
  const int nb = ((int)blockIdx.x & 7) << 7;

  const int srow = (w << 5) + (l >> 2);
  const int sseg = (l & 3) << 3;
  const u16* Ag0 = Ctx + (size_t)(mb + srow) * 1024 + sseg;
  const u16* Bg0 = Bw + (size_t)(nb + srow) * 1024 + sseg;
  u16* Al0 = As + srow * 32 + sseg;
  u16* Bl0 = Bs + srow * 32 + sseg;

  f32x4 acc[4][4] = {};
  const int ar = (wr << 6) + ln;
  const int br = (wc << 6) + ln;

  for (int k0 = 0; k0 < 1024; k0 += 32) {
    glds16(Ag0 + k0, Al0);
    glds16(Ag0 + 16384 + k0, Al0 + 512);
    glds16(Bg0 + k0, Bl0);
    glds16(Bg0 + 16384 + k0, Bl0 + 512);
    __syncthreads();
    bf16x8 aa[4], bb[4];
#pragma unroll
    for (int mt = 0; mt < 4; ++mt) aa[mt] = *(const bf16x8*)&As[(ar + (mt << 4)) * 32 + kg8];
#pragma unroll
    for (int nt = 0; nt < 4; ++nt) bb[nt] = *(const bf16x8*)&Bs[(br + (nt << 4)) * 32 + kg8];
#pragma unroll
    for (int mt = 0; mt < 4; ++mt)
#pragma unroll
      for (int nt = 0; nt < 4; ++nt)
        acc[mt][nt] = __builtin_amdgcn_mfma_f32_16x16x32_bf16(aa[mt], bb[nt], acc[mt][nt], 0, 0, 0);
    __syncthreads();
  }
#pragma unroll
  for (int mt = 0; mt < 4; ++mt) {
    const int m0 = mb + (wr << 6) + (mt << 4) + (lg << 2);
#pragma unroll
    for (int nt = 0; nt < 4; ++nt) {
      const int n = nb + (wc << 6) + (nt << 4) + ln;
      const float bval = bO[n];
#pragma unroll
      for (int r = 0; r < 4; ++r)
        Out[(size_t)(m0 + r) * 1024 + n] = acc[mt][nt][r] + bval;
    }
  }
}

// ---- attention: fused exp + reg-rotating prefetch + packed bf16 conversions ----
__global__ __launch_bounds__(256, 2) void attn_kernel(
    const u16* __restrict__ Qup, const u16* __restrict__ Kf,
    const u16* __restrict__ Vf, const unsigned long long* __restrict__ Mb,
    u16* __restrict__ Ctx, u16* __restrict__ Pp) {
  __shared__ u16 P_lds[16 * 1024];   // unnormalized exp(s-4), XOR-swizzled rows
  __shared__ float red_s[4][16];
  __shared__ float invs[16];

  const int tid = threadIdx.x;
  const int w = tid >> 6, l = tid & 63;
  const int ln = l & 15, lg = l >> 4;
  const int kg8 = lg << 3;

  // XCD-bijective swizzle: XCD x owns heads {2x,2x+1} for all (b, qtile)
  const int bid = (int)blockIdx.x;
  const int swz = ((bid & 7) << 9) | (bid >> 3);
  const int qt = swz & 63;
  const int qb = qt << 4;
  const int b = (swz >> 6) & 7;
  const int hs = swz >> 9;           // head pair 0..7

  // pre-packed mask bits: ONE load (was 64 scalar loads)
  const unsigned long long mbits = Mb[((((size_t)b << 6) + qt) << 8) + tid];

  u32x4 accp[8];   // packed-bf16 partial plane accumulator (row = tid>>4)

#pragma unroll 1
  for (int hh = 0; hh < 2; ++hh) {
    const int h = (hs << 1) + hh;
    const size_t bh = (size_t)(b * 16 + h);
    const u16* Qp = Qup + ((bh << 10) + qb) * 64;
    const u16* Kb = Kf + (bh << 16);                     // fragment-major
    const u16* Vb = Vf + (bh << 16) + ((size_t)w << 14);

    const bf16x8 qa0 = *(const bf16x8*)&Qp[ln * 64 + kg8];
    const bf16x8 qa1 = *(const bf16x8*)&Qp[ln * 64 + 32 + kg8];

    // K register pipeline, depth 3 (static rotation -> stays in VGPRs)
    bf16x8 ka[3], kb[3];
#pragma unroll
    for (int p = 0; p < 3; ++p) {
      const int To = ((w << 4) + p) << 10;
      ka[p] = *(const bf16x8*)&Kb[To + (l << 3)];
      kb[p] = *(const bf16x8*)&Kb[To + 512 + (l << 3)];
    }

    // Fused QK^T -> mask -> exp(s-4) -> P_lds (packed conversions)
    float rsum[4] = {0, 0, 0, 0};
#pragma unroll
    for (int t = 0; t < 16; ++t) {
      const int s = t % 3;                 // constant after unroll
      const bf16x8 k0 = ka[s], k1 = kb[s];
      if (t + 3 < 16) {                    // prefetch 3 tiles ahead
        const int To = ((w << 4) + t + 3) << 10;
        ka[s] = *(const bf16x8*)&Kb[To + (l << 3)];
        kb[s] = *(const bf16x8*)&Kb[To + 512 + (l << 3)];
      }
      f32x4 c = {0, 0, 0, 0};
      c = __builtin_amdgcn_mfma_f32_16x16x32_bf16(qa0, k0, c, 0, 0, 0);
      c = __builtin_amdgcn_mfma_f32_16x16x32_bf16(qa1, k1, c, 0, 0, 0);
      const int key = (w << 8) + (t << 4) + ln;
      float p[4];
#pragma unroll
      for (int r = 0; r < 4; ++r) {
        p[r] = ((mbits >> ((t << 2) + r)) & 1ull) ? 0.0f : __expf(c[r] - 4.0f);
        rsum[r] += p[r];
      }
      const u32 pk01 = cvtpk(p[0], p[1]);
      const u32 pk23 = cvtpk(p[2], p[3]);
      const int r0 = lg << 2;
      *(u16*)((char*)P_lds + ((((r0 + 0) << 11) + (key << 1)) ^ (((r0 + 0) & 7) << 4))) = (u16)pk01;
      *(u16*)((char*)P_lds + ((((r0 + 1) << 11) + (key << 1)) ^ (((r0 + 1) & 7) << 4))) = (u16)(pk01 >> 16);
      *(u16*)((char*)P_lds + ((((r0 + 2) << 11) + (key << 1)) ^ (((r0 + 2) & 7) << 4))) = (u16)pk23;
      *(u16*)((char*)P_lds + ((((r0 + 3) << 11) + (key << 1)) ^ (((r0 + 3) & 7) << 4))) = (u16)(pk23 >> 16);
    }
    // row sums across the 16 ln lanes
#pragma unroll
    for (int off = 1; off < 16; off <<= 1) {
#pragma unroll
      for (int r = 0; r < 4; ++r) rsum[r] += __shfl_xor(rsum[r], off);
    }
    if (ln == 0) {
#pragma unroll
      for (int r = 0; r < 4; ++r) red_s[w][(lg << 2) + r] = rsum[r];
    }

    // V register pipeline, depth 4; prologue overlaps the barrier wait
    bf16x8 vr[4];
#pragma unroll
    for (int p = 0; p < 4; ++p)
      vr[p] = *(const bf16x8*)&Vb[(p << 9) + (l << 3)];

    __syncthreads();                                   // P + red_s ready
    float inv[4];
#pragma unroll
    for (int r = 0; r < 4; ++r) {
      const int row = (lg << 2) + r;
      inv[r] = 1.0f / (red_s[0][row] + red_s[1][row] + red_s[2][row] + red_s[3][row]);
    }
    if (ln == 0) {
#pragma unroll
      for (int r = 0; r < 4; ++r) invs[(lg << 2) + r] = inv[r];
    }

    // PV on unnormalized P; V prefetched 4 tiles ahead in registers.
    f32x4 c0 = {0, 0, 0, 0}, c1 = {0, 0, 0, 0};
#pragma unroll
    for (int kk = 0; kk < 32; ++kk) {
      const int s = kk & 3;
      const bf16x8 vb = vr[s];
      if (kk + 4 < 32)
        vr[s] = *(const bf16x8*)&Vb[((kk + 4) << 9) + (l << 3)];
      const int a0 = ((ln << 11) + (((kk << 5) + kg8) << 1)) ^ ((ln & 7) << 4);
      const bf16x8 pa = *(const bf16x8*)((const char*)P_lds + a0);
      if (kk & 1)
        c1 = __builtin_amdgcn_mfma_f32_16x16x32_bf16(pa, vb, c1, 0, 0, 0);
      else
        c0 = __builtin_amdgcn_mfma_f32_16x16x32_bf16(pa, vb, c0, 0, 0, 0);
    }
    {
      const u32 q01 = cvtpk((c0[0] + c1[0]) * inv[0], (c0[1] + c1[1]) * inv[1]);
      const u32 q23 = cvtpk((c0[2] + c1[2]) * inv[2], (c0[3] + c1[3]) * inv[3]);
      u16* Cp = &Ctx[(((size_t)b << 10) + qb + (lg << 2)) * 1024 + (h << 6) + (w << 4) + ln];
      Cp[0] = (u16)q01;
      Cp[1024] = (u16)(q01 >> 16);
      Cp[2048] = (u16)q23;
      Cp[3072] = (u16)(q23 >> 16);
    }

    // attn_mean plane: packed readback P_lds * invs[row], coalesced
    {
      const int row = tid >> 4;
      const float iv = invs[row];
      u16* Pg = Pp + ((size_t)hs << 23) + (((size_t)b << 10) + qb + row) * 1024;
#pragma unroll
      for (int i = 0; i < 8; ++i) {
        const int chunk = (tid & 15) + (i << 4);
        const int bo_ = ((row << 11) + (chunk << 4)) ^ ((row & 7) << 4);
        const u32x4 pu = *(const u32x4*)((const char*)P_lds + bo_);
        u32x4 o;
#pragma unroll
        for (int j = 0; j < 4; ++j) {
          const float plo = __builtin_bit_cast(float, pu[j] << 16) * iv;
          const float phi = __builtin_bit_cast(float, pu[j] & 0xFFFF0000u) * iv;
          if (hh == 0) {
            o[j] = cvtpk(plo, phi);
          } else {
            const u32 a = accp[i][j];
            const float alo = __builtin_bit_cast(float, a << 16);
            const float ahi = __builtin_bit_cast(float, a & 0xFFFF0000u);
            o[j] = cvtpk(alo + plo, ahi + phi);
          }
        }
        if (hh == 0) accp[i] = o;
        else *(u32x4*)&Pg[chunk << 3] = o;
      }
    }
    __syncthreads();                                   // LDS reuse next head
  }
}

// ---- combine: amean = sum of 8 pair-planes / 16, fp32 out ----
__global__ __launch_bounds__(256) void combine(
    const u16* __restrict__ Pp, float* __restrict__ Am) {
  const size_t i = ((size_t)blockIdx.x * 256 + threadIdx.x) * 8;
  float s[8] = {0, 0, 0, 0, 0, 0, 0, 0};
#pragma unroll
  for (int p = 0; p < 8; ++p) {
    const u16x4* q = (const u16x4*)&Pp[(size_t)p * 8388608 + i];
    const u16x4 a = q[0], c = q[1];
#pragma unroll
    for (int r = 0; r < 4; ++r) { s[r] += bf2f(a[r]); s[r + 4] += bf2f(c[r]); }
  }
  f32x4 lo, hi;
#pragma unroll
  for (int r = 0; r < 4; ++r) { lo[r] = s[r] * 0.0625f; hi[r] = s[r + 4] * 0.0625f; }
  *(f32x4*)&Am[i] = lo;
  *(f32x4*)&Am[i + 4] = hi;
}

extern "C" void kernel_launch(void* const* d_in, const int* in_sizes, int n_in,
                              void* d_out, int out_size, void* d_ws, size_t ws_size,
                              hipStream_t stream) {
  const float* k_in = (const float*)d_in[0];
  const float* v_in = (const float*)d_in[1];
  const float* q_in = (const float*)d_in[2];
  const int* mask = (const int*)d_in[3];
  const float* Wk = (const float*)d_in[4];
  const float* bk = (const float*)d_in[5];
  const float* Wv = (const float*)d_in[6];
  const float* bv = (const float*)d_in[7];
  const float* Wq = (const float*)d_in[8];
  const float* bq = (const float*)d_in[9];
  const float* Wo = (const float*)d_in[10];
  const float* bo = (const float*)d_in[11];

  float* out = (float*)d_out;                       // [8,1024,1024] f32
  float* amean = out + (size_t)8 * 1024 * 1024;     // [8,1024,1024] f32

  // Mask-bit table lives in the amean half of d_out: written by maskpack,
  // read by attn, then fully overwritten by combine (stream-ordered).
  unsigned long long* Mb = (unsigned long long*)amean;   // 1 MB

  // ws layout (u16 units): WT 4M | Pp 8x8M (Xb 24M aliased, dead before attn)
  //  | Kf 8M | Vf 8M | Qup 8M | Ctx 8M  -> 104857600 u16 = 209.7 MB (proven)
  u16* ws = (u16*)d_ws;
  u16* WT = ws;
  u16* Xb = ws + 4194304;
  u16* Pp = ws + 4194304;
  u16* Kf   = ws + 71303168;
  u16* Vf   = ws + 79691776;
  u16* Qup  = ws + 88080384;
  u16* Ctx  = ws + 96468992;

  xcvt<<<2048, 256, 0, stream>>>(k_in, v_in, q_in, Xb);
  transpose_w<<<dim3(1024, 4), dim3(256), 0, stream>>>(Wk, Wv, Wq, Wo, WT);
  maskpack<<<dim3(64, 8), dim3(256), 0, stream>>>(mask, Mb);
  gemm_qkv<<<dim3(512, 3), dim3(256), 0, stream>>>(
      Xb, WT, bk, bv, bq, Kf, Vf, Qup);
  attn_kernel<<<dim3(4096), dim3(256), 0, stream>>>(
      Qup, Kf, Vf, Mb, Ctx, Pp);
  combine<<<4096, 256, 0, stream>>>(Pp, amean);
  gemm_out<<<512, 256, 0, stream>>>(Ctx, WT, bo, out);
}

// Round 11
// 297.090 us; speedup vs baseline: 2.1621x; 1.0497x over previous
//
#include <hip/hip_runtime.h>
#include <hip/hip_bf16.h>

typedef unsigned short u16;
typedef unsigned int u32;
typedef __attribute__((ext_vector_type(8))) short bf16x8;
typedef __attribute__((ext_vector_type(4))) float f32x4;
typedef __attribute__((ext_vector_type(4))) u16 u16x4;
typedef __attribute__((ext_vector_type(4))) u32 u32x4;

#define DEV static __device__ __forceinline__

DEV u16 f2bf(float x) {
  unsigned u = __builtin_bit_cast(unsigned, x);
  u += 0x7fffu + ((u >> 16) & 1u);   // RNE (finite values)
  return (u16)(u >> 16);
}
DEV float bf2f(u16 u) { return __builtin_bit_cast(float, ((unsigned)u) << 16); }

DEV u32 cvtpk(float lo, float hi) {   // packed f32->bf16 (RNE), gfx950
  u32 r;
  asm("v_cvt_pk_bf16_f32 %0, %1, %2" : "=v"(r) : "v"(lo), "v"(hi));
  return r;
}

DEV void glds16(const u16* g, u16* l) {
  __builtin_amdgcn_global_load_lds(
      (const __attribute__((address_space(1))) void*)g,
      (__attribute__((address_space(3))) void*)l, 16, 0, 0);
}

// ---- X convert: k,v,q fp32 -> Xb bf16 [3][8388608] (order: k, v, q) ----
__global__ __launch_bounds__(256) void xcvt(
    const float* __restrict__ k, const float* __restrict__ v,
    const float* __restrict__ q, u16* __restrict__ Xb) {
  const size_t i0 = (size_t)blockIdx.x * 256 + threadIdx.x;
  for (size_t t = i0; t < 6291456; t += 524288) {
    const size_t e = t * 4;
    const float* src = (e < 8388608) ? k + e
                     : (e < 16777216) ? v + (e - 8388608)
                     : q + (e - 16777216);
    const f32x4 x = *(const f32x4*)src;
    u16x4 o;
#pragma unroll
    for (int r = 0; r < 4; ++r) o[r] = f2bf(x[r]);
    *(u16x4*)&Xb[e] = o;
  }
}

// ---- transpose+convert weights: out_bf16[n*1024+k] = in_f32[k*1024+n] ----
__global__ __launch_bounds__(256) void transpose_w(
    const float* __restrict__ w0, const float* __restrict__ w1,
    const float* __restrict__ w2, const float* __restrict__ w3,
    u16* __restrict__ out) {
  __shared__ u16 tile[32][33];
  const int mat = blockIdx.y;
  const float* in = (mat == 0) ? w0 : (mat == 1) ? w1 : (mat == 2) ? w2 : w3;
  u16* o = out + (size_t)mat * 1048576;
  const int bk = ((int)blockIdx.x & 31) << 5;
  const int bn = ((int)blockIdx.x >> 5) << 5;
  const int tx = threadIdx.x & 31, ty = threadIdx.x >> 5;
#pragma unroll
  for (int i = 0; i < 32; i += 8)
    tile[ty + i][tx] = f2bf(in[(size_t)(bk + ty + i) * 1024 + bn + tx]);
  __syncthreads();
#pragma unroll
  for (int i = 0; i < 32; i += 8)
    o[(size_t)(bn + ty + i) * 1024 + bk + tx] = tile[tx][ty + i];
}

// ---- maskpack: per-(b,qtile,lane) 64-bit mask word, matching attn's layout ----
// bit (t*4+r) for (row = 4*(l>>4)+r, key = (tid>>6)*256 + t*16 + (l&15))
__global__ __launch_bounds__(256) void maskpack(
    const int* __restrict__ mask, unsigned long long* __restrict__ Mb) {
  const int qt = blockIdx.x, b = blockIdx.y;
  const int tid = threadIdx.x;
  const int w = tid >> 6, l = tid & 63;
  const int ln = l & 15, lg = l >> 4;
  const int* Mp = mask + ((size_t)b << 20) + ((size_t)(qt << 4) << 10);
  unsigned long long m = 0ull;
#pragma unroll
  for (int t = 0; t < 16; ++t) {
    const int key = (w << 8) + (t << 4) + ln;
#pragma unroll
    for (int r = 0; r < 4; ++r) {
      const int row = (lg << 2) + r;
      if (Mp[((size_t)row << 10) + key] != 0) m |= 1ull << ((t << 2) + r);
    }
  }
  Mb[((((size_t)b << 6) + qt) << 8) + tid] = m;
}

// ---- m97-style GEMM: 128x128 tile, BK=32, global_load_lds staging ----
// Outputs (fragment-major for attention):
//  mode 0: Kf[bh][T][half][lg][ln][8]  (65536 u16 per bh)
//  mode 1: Vf[bh][wv][kk][lg][ln][8]   (65536 u16 per bh)
//  mode 2: Qup [bh][s][64], scaled 1/8
__global__ __launch_bounds__(256) void gemm_qkv(
    const u16* __restrict__ Xb, const u16* __restrict__ WTall,
    const float* __restrict__ bK, const float* __restrict__ bV,
    const float* __restrict__ bQ,
    u16* __restrict__ Kup, u16* __restrict__ VupT, u16* __restrict__ Qup) {
  __shared__ u16 As[4096];   // [128][32] linear
  __shared__ u16 Bs[4096];
  const int mode = blockIdx.y;
  const u16* A = Xb + (size_t)mode * 8388608;
  const u16* Bw = WTall + (size_t)mode * 1048576;
  const float* bias = (mode == 0) ? bK : (mode == 1) ? bV : bQ;

  const int tid = threadIdx.x;
  const int w = tid >> 6, l = tid & 63;
  const int ln = l & 15, lg = l >> 4, kg8 = lg << 3;
  const int wr = w >> 1, wc = w & 1;
  const int mb = ((int)blockIdx.x >> 3) << 7;
  const int nb = ((int)blockIdx.x & 7) << 7;

  const int srow = (w << 5) + (l >> 2);
  const int sseg = (l & 3) << 3;
  const u16* Ag0 = A + (size_t)(mb + srow) * 1024 + sseg;
  const u16* Bg0 = Bw + (size_t)(nb + srow) * 1024 + sseg;
  u16* Al0 = As + srow * 32 + sseg;
  u16* Bl0 = Bs + srow * 32 + sseg;

  f32x4 acc[4][4] = {};
  const int ar = (wr << 6) + ln;
  const int br = (wc << 6) + ln;

  for (int k0 = 0; k0 < 1024; k0 += 32) {
    glds16(Ag0 + k0, Al0);
    glds16(Ag0 + 16384 + k0, Al0 + 512);
    glds16(Bg0 + k0, Bl0);
    glds16(Bg0 + 16384 + k0, Bl0 + 512);
    __syncthreads();
    bf16x8 aa[4], bb[4];
#pragma unroll
    for (int mt = 0; mt < 4; ++mt) aa[mt] = *(const bf16x8*)&As[(ar + (mt << 4)) * 32 + kg8];
#pragma unroll
    for (int nt = 0; nt < 4; ++nt) bb[nt] = *(const bf16x8*)&Bs[(br + (nt << 4)) * 32 + kg8];
#pragma unroll
    for (int mt = 0; mt < 4; ++mt)
#pragma unroll
      for (int nt = 0; nt < 4; ++nt)
        acc[mt][nt] = __builtin_amdgcn_mfma_f32_16x16x32_bf16(aa[mt], bb[nt], acc[mt][nt], 0, 0, 0);
    __syncthreads();
  }

  const float scale = (mode == 2) ? 0.125f : 1.0f;
#pragma unroll
  for (int mt = 0; mt < 4; ++mt) {
    const int m0 = mb + (wr << 6) + (mt << 4) + (lg << 2);
    const int bb_ = m0 >> 10, s0 = m0 & 1023;
#pragma unroll
    for (int nt = 0; nt < 4; ++nt) {
      const int n = nb + (wc << 6) + (nt << 4) + ln;
      const float bval = bias[n];
      const int h = n >> 6, dh = n & 63;
      const size_t bh = (size_t)(bb_ * 16 + h);
      if (mode == 1) {
        // Vf[bh][wv=dh>>4][kk=s>>5][lgv=(s>>3)&3][lnv=dh&15][e=s&7]
        const int wv = dh >> 4, lnv = dh & 15;
        const int kk = s0 >> 5, lgv = (s0 >> 3) & 3, e0 = s0 & 7;
        u16x4 pk;
#pragma unroll
        for (int r = 0; r < 4; ++r) pk[r] = f2bf(acc[mt][nt][r] + bval);
        *(u16x4*)&VupT[(bh << 16) + (wv << 14) + (kk << 9) + (lgv << 7) +
                       (lnv << 3) + e0] = pk;
      } else if (mode == 0) {
        // Kf[bh][T=s>>4][half=dh>>5][lg2=(dh>>3)&3][ln2=s&15][e=dh&7]
        const int half = dh >> 5, lg2 = (dh >> 3) & 3, e = dh & 7;
        const int T = s0 >> 4;
        u16* base = Kup + (bh << 16) + (T << 10) + (half << 9) + (lg2 << 7) + e;
#pragma unroll
        for (int r = 0; r < 4; ++r)
          base[((s0 & 15) + r) << 3] = f2bf(acc[mt][nt][r] + bval);
      } else {
#pragma unroll
        for (int r = 0; r < 4; ++r)
          Qup[((bh << 10) + s0 + r) * 64 + dh] =
              f2bf((acc[mt][nt][r] + bval) * scale);
      }
    }
  }
}

// ---- out-proj: Out_f32 = Ctx_bf16 @ WoT + bo ----
__global__ __launch_bounds__(256) void gemm_out(
    const u16* __restrict__ Ctx, const u16* __restrict__ WTall,
    const float* __restrict__ bO, float* __restrict__ Out) {
  __shared__ u16 As[4096];
  __shared__ u16 Bs[4096];
  const u16* Bw = WTall + 3145728;

  const int tid = threadIdx.x;
  const int w = tid >> 6, l = tid & 63;
  const int ln = l & 15, lg = l >> 4, kg8 = lg << 3;
  const int wr = w >> 1, wc = w & 1;
  const int mb = ((int)blockIdx.x >> 3) << 7;
  const int nb = ((int)blockIdx.x & 7) << 7;

  const int srow = (w << 5) + (l >> 2);
  const int sseg = (l & 3) << 3;
  const u16* Ag0 = Ctx + (size_t)(mb + srow) * 1024 + sseg;
  const u16* Bg0 = Bw + (size_t)(nb + srow) * 1024 + sseg;
  u16* Al0 = As + srow * 32 + sseg;
  u16* Bl0 = Bs + srow * 32 + sseg;

  f32x4 acc[4][4] = {};
  const int ar = (wr << 6) + ln;
  const int br = (wc << 6) + ln;

  for (int k0 = 0; k0 < 1024; k0 += 32) {
    glds16(Ag0 + k0, Al0);
    glds16(Ag0 + 16384 + k0, Al0 + 512);
    glds16(Bg0 + k0, Bl0);
    glds16(Bg0 + 16384 + k0, Bl0 + 512);
    __syncthreads();
    bf16x8 aa[4], bb[4];
#pragma unroll
    for (int mt = 0; mt < 4; ++mt) aa[mt] = *(const bf16x8*)&As[(ar + (mt << 4)) * 32 + kg8];
#pragma unroll
    for (int nt = 0; nt < 4; ++nt) bb[nt] = *(const bf16x8*)&Bs[(br + (nt << 4)) * 32 + kg8];
#pragma unroll
    for (int mt = 0; mt < 4; ++mt)
#pragma unroll
      for (int nt = 0; nt < 4; ++nt)
        acc[mt][nt] = __builtin_amdgcn_mfma_f32_16x16x32_bf16(aa[mt], bb[nt], acc[mt][nt], 0, 0, 0);
    __syncthreads();
  }
#pragma unroll
  for (int mt = 0; mt < 4; ++mt) {
    const int m0 = mb + (wr << 6) + (mt << 4) + (lg << 2);
#pragma unroll
    for (int nt = 0; nt < 4; ++nt) {
      const int n = nb + (wc << 6) + (nt << 4) + ln;
      const float bval = bO[n];
#pragma unroll
      for (int r = 0; r < 4; ++r)
        Out[(size_t)(m0 + r) * 1024 + n] = acc[mt][nt][r] + bval;
    }
  }
}

// ---- attention: 512 blocks, ALL 16 heads per block; amean written directly ----
__global__ __launch_bounds__(256, 2) void attn_kernel(
    const u16* __restrict__ Qup, const u16* __restrict__ Kf,
    const u16* __restrict__ Vf, const unsigned long long* __restrict__ Mb,
    u16* __restrict__ Ctx, float* __restrict__ Am) {
  __shared__ u16 P_lds[16 * 1024];   // unnormalized exp(s-4), XOR-swizzled rows
  __shared__ float red_s[4][16];
  __shared__ float invs[16];

  const int tid = threadIdx.x;
  const int w = tid >> 6, l = tid & 63;
  const int ln = l & 15, lg = l >> 4;
  const int kg8 = lg << 3;

  // XCD swizzle: XCD x owns batch b = x (K+V = 4 MB = one L2); all co-resident
  // qtile blocks walk heads in lockstep -> instantaneous set ~512 KB.
  const int bid = (int)blockIdx.x;
  const int b = bid & 7;
  const int qt = bid >> 3;
  const int qb = qt << 4;

  // pre-packed mask bits: ONE load per block
  const unsigned long long mbits = Mb[((((size_t)b << 6) + qt) << 8) + tid];

  u32x4 accp[8];   // packed-bf16 attn_mean accumulator (row = tid>>4 layout)

#pragma unroll 1
  for (int hh = 0; hh < 16; ++hh) {
    const size_t bh = (size_t)(b * 16 + hh);
    const u16* Qp = Qup + ((bh << 10) + qb) * 64;
    const u16* Kb = Kf + (bh << 16);                     // fragment-major
    const u16* Vb = Vf + (bh << 16) + ((size_t)w << 14);

    const bf16x8 qa0 = *(const bf16x8*)&Qp[ln * 64 + kg8];
    const bf16x8 qa1 = *(const bf16x8*)&Qp[ln * 64 + 32 + kg8];

    // K register pipeline, depth 3 (static rotation -> stays in VGPRs)
    bf16x8 ka[3], kb[3];
#pragma unroll
    for (int p = 0; p < 3; ++p) {
      const int To = ((w << 4) + p) << 10;
      ka[p] = *(const bf16x8*)&Kb[To + (l << 3)];
      kb[p] = *(const bf16x8*)&Kb[To + 512 + (l << 3)];
    }

    // Fused QK^T -> mask -> exp(s-4) -> P_lds (packed conversions)
    float rsum[4] = {0, 0, 0, 0};
#pragma unroll
    for (int t = 0; t < 16; ++t) {
      const int s = t % 3;                 // constant after unroll
      const bf16x8 k0 = ka[s], k1 = kb[s];
      if (t + 3 < 16) {                    // prefetch 3 tiles ahead
        const int To = ((w << 4) + t + 3) << 10;
        ka[s] = *(const bf16x8*)&Kb[To + (l << 3)];
        kb[s] = *(const bf16x8*)&Kb[To + 512 + (l << 3)];
      }
      f32x4 c = {0, 0, 0, 0};
      c = __builtin_amdgcn_mfma_f32_16x16x32_bf16(qa0, k0, c, 0, 0, 0);
      c = __builtin_amdgcn_mfma_f32_16x16x32_bf16(qa1, k1, c, 0, 0, 0);
      const int key = (w << 8) + (t << 4) + ln;
      float p[4];
#pragma unroll
      for (int r = 0; r < 4; ++r) {
        p[r] = ((mbits >> ((t << 2) + r)) & 1ull) ? 0.0f : __expf(c[r] - 4.0f);
        rsum[r] += p[r];
      }
      const u32 pk01 = cvtpk(p[0], p[1]);
      const u32 pk23 = cvtpk(p[2], p[3]);
      const int r0 = lg << 2;
      *(u16*)((char*)P_lds + ((((r0 + 0) << 11) + (key << 1)) ^ (((r0 + 0) & 7) << 4))) = (u16)pk01;
      *(u16*)((char*)P_lds + ((((r0 + 1) << 11) + (key << 1)) ^ (((r0 + 1) & 7) << 4))) = (u16)(pk01 >> 16);
      *(u16*)((char*)P_lds + ((((r0 + 2) << 11) + (key << 1)) ^ (((r0 + 2) & 7) << 4))) = (u16)pk23;
      *(u16*)((char*)P_lds + ((((r0 + 3) << 11) + (key << 1)) ^ (((r0 + 3) & 7) << 4))) = (u16)(pk23 >> 16);
    }
    // row sums across the 16 ln lanes
#pragma unroll
    for (int off = 1; off < 16; off <<= 1) {
#pragma unroll
      for (int r = 0; r < 4; ++r) rsum[r] += __shfl_xor(rsum[r], off);
    }
    if (ln == 0) {
#pragma unroll
      for (int r = 0; r < 4; ++r) red_s[w][(lg << 2) + r] = rsum[r];
    }

    // V register pipeline, depth 4; prologue overlaps the barrier wait
    bf16x8 vr[4];
#pragma unroll
    for (int p = 0; p < 4; ++p)
      vr[p] = *(const bf16x8*)&Vb[(p << 9) + (l << 3)];

    __syncthreads();                                   // P + red_s ready
    float inv[4];
#pragma unroll
    for (int r = 0; r < 4; ++r) {
      const int row = (lg << 2) + r;
      inv[r] = 1.0f / (red_s[0][row] + red_s[1][row] + red_s[2][row] + red_s[3][row]);
    }
    if (ln == 0) {
#pragma unroll
      for (int r = 0; r < 4; ++r) invs[(lg << 2) + r] = inv[r];
    }

    // PV on unnormalized P; V prefetched 4 tiles ahead in registers.
    f32x4 c0 = {0, 0, 0, 0}, c1 = {0, 0, 0, 0};
#pragma unroll
    for (int kk = 0; kk < 32; ++kk) {
      const int s = kk & 3;
      const bf16x8 vb = vr[s];
      if (kk + 4 < 32)
        vr[s] = *(const bf16x8*)&Vb[((kk + 4) << 9) + (l << 3)];
      const int a0 = ((ln << 11) + (((kk << 5) + kg8) << 1)) ^ ((ln & 7) << 4);
      const bf16x8 pa = *(const bf16x8*)((const char*)P_lds + a0);
      if (kk & 1)
        c1 = __builtin_amdgcn_mfma_f32_16x16x32_bf16(pa, vb, c1, 0, 0, 0);
      else
        c0 = __builtin_amdgcn_mfma_f32_16x16x32_bf16(pa, vb, c0, 0, 0, 0);
    }
    {
      const u32 q01 = cvtpk((c0[0] + c1[0]) * inv[0], (c0[1] + c1[1]) * inv[1]);
      const u32 q23 = cvtpk((c0[2] + c1[2]) * inv[2], (c0[3] + c1[3]) * inv[3]);
      u16* Cp = &Ctx[(((size_t)b << 10) + qb + (lg << 2)) * 1024 + (hh << 6) + (w << 4) + ln];
      Cp[0] = (u16)q01;
      Cp[1024] = (u16)(q01 >> 16);
      Cp[2048] = (u16)q23;
      Cp[3072] = (u16)(q23 >> 16);
    }

    // attn_mean: packed readback P_lds * invs[row], accumulate across 16 heads
    {
      const int row = tid >> 4;
      const float iv = invs[row];
#pragma unroll
      for (int i = 0; i < 8; ++i) {
        const int chunk = (tid & 15) + (i << 4);
        const int bo_ = ((row << 11) + (chunk << 4)) ^ ((row & 7) << 4);
        const u32x4 pu = *(const u32x4*)((const char*)P_lds + bo_);
        u32x4 o;
#pragma unroll
        for (int j = 0; j < 4; ++j) {
          const float plo = __builtin_bit_cast(float, pu[j] << 16) * iv;
          const float phi = __builtin_bit_cast(float, pu[j] & 0xFFFF0000u) * iv;
          if (hh == 0) {
            o[j] = cvtpk(plo, phi);
          } else {
            const u32 a = accp[i][j];
            const float alo = __builtin_bit_cast(float, a << 16);
            const float ahi = __builtin_bit_cast(float, a & 0xFFFF0000u);
            o[j] = cvtpk(alo + plo, ahi + phi);
          }
        }
        accp[i] = o;
      }
    }
    __syncthreads();                                   // LDS reuse next head
  }

  // final: amean = accp / 16, fp32, coalesced
  {
    const int row = tid >> 4;
    float* Ag = Am + (((size_t)b << 10) + qb + row) * 1024;
#pragma unroll
    for (int i = 0; i < 8; ++i) {
      const int chunk = (tid & 15) + (i << 4);
      f32x4 o0, o1;
#pragma unroll
      for (int j = 0; j < 4; ++j) {
        const float lo = __builtin_bit_cast(float, accp[i][j] << 16) * 0.0625f;
        const float hi = __builtin_bit_cast(float, accp[i][j] & 0xFFFF0000u) * 0.0625f;
        if (j < 2) { o0[2 * j] = lo; o0[2 * j + 1] = hi; }
        else       { o1[2 * (j - 2)] = lo; o1[2 * (j - 2) + 1] = hi; }
      }
      *(f32x4*)&Ag[chunk << 3] = o0;
      *(f32x4*)&Ag[(chunk << 3) + 4] = o1;
    }
  }
}

extern "C" void kernel_launch(void* const* d_in, const int* in_sizes, int n_in,
                              void* d_out, int out_size, void* d_ws, size_t ws_size,
                              hipStream_t stream) {
  const float* k_in = (const float*)d_in[0];
  const float* v_in = (const float*)d_in[1];
  const float* q_in = (const float*)d_in[2];
  const int* mask = (const int*)d_in[3];
  const float* Wk = (const float*)d_in[4];
  const float* bk = (const float*)d_in[5];
  const float* Wv = (const float*)d_in[6];
  const float* bv = (const float*)d_in[7];
  const float* Wq = (const float*)d_in[8];
  const float* bq = (const float*)d_in[9];
  const float* Wo = (const float*)d_in[10];
  const float* bo = (const float*)d_in[11];

  float* out = (float*)d_out;                       // [8,1024,1024] f32
  float* amean = out + (size_t)8 * 1024 * 1024;     // [8,1024,1024] f32

  // ws layout (u16 units): WT 4M | Xb 24M | Mb 0.5M | ... | Kf | Vf | Qup | Ctx
  // total 209.7 MB (proven).
  u16* ws = (u16*)d_ws;
  u16* WT = ws;
  u16* Xb = ws + 4194304;
  unsigned long long* Mb = (unsigned long long*)(ws + 29360128);  // 1 MB
  u16* Kf   = ws + 71303168;
  u16* Vf   = ws + 79691776;
  u16* Qup  = ws + 88080384;
  u16* Ctx  = ws + 96468992;

  xcvt<<<2048, 256, 0, stream>>>(k_in, v_in, q_in, Xb);
  transpose_w<<<dim3(1024, 4), dim3(256), 0, stream>>>(Wk, Wv, Wq, Wo, WT);
  maskpack<<<dim3(64, 8), dim3(256), 0, stream>>>(mask, Mb);
  gemm_qkv<<<dim3(512, 3), dim3(256), 0, stream>>>(
      Xb, WT, bk, bv, bq, Kf, Vf, Qup);
  attn_kernel<<<dim3(512), dim3(256), 0, stream>>>(
      Qup, Kf, Vf, Mb, Ctx, amean);
  gemm_out<<<512, 256, 0, stream>>>(Ctx, WT, bo, out);
}